// Round 7
// baseline (764.717 us; speedup 1.0000x reference)
//
#include <hip/hip_runtime.h>
#include <hip/hip_bf16.h>

#define EDGES 1000000
#define NNODES 50000
#define NG 512
#define NTILES 15625  // EDGES/64
#define NCOLB 50176   // col-hist bins rounded to 196*256

typedef __attribute__((ext_vector_type(8))) short bf16x8;
typedef __attribute__((ext_vector_type(4))) float f32x4;

__device__ __forceinline__ unsigned short f2bf(float f){
  unsigned u = __float_as_uint(f);
  u += 0x7fffu + ((u >> 16) & 1u);
  return (unsigned short)(u >> 16);
}
__device__ __forceinline__ float bf2f(unsigned short h){
  return __uint_as_float(((unsigned)h) << 16);
}
__device__ __forceinline__ unsigned pk2bf(float x, float y){
  __hip_bfloat162 h = __float22bfloat162_rn(make_float2(x, y));
  union { __hip_bfloat162 h; unsigned u; } cv; cv.h = h;
  return cv.u;
}
// XCD-aware swizzle: contiguous tile ranges per XCD. TRUE BIJECTION.
__device__ __forceinline__ int xcd_swizzle(int bid, int nb){
  int nb8 = nb & ~7;
  if (bid >= nb8) return bid;
  int per = nb8 >> 3;
  return (bid & 7) * per + (bid >> 3);
}

// ---------------- prep: emb->bf16, W1->w1tn, W2->w2t ----------------
__global__ void prep_all(const float* __restrict__ emb, const float* __restrict__ W1,
                         const float* __restrict__ W2,
                         unsigned short* __restrict__ emb_bf,
                         unsigned short* __restrict__ w1tn, unsigned short* __restrict__ w2t){
  int i = blockIdx.x * 256 + threadIdx.x;
  if (i < NNODES * 64){
    emb_bf[i] = f2bf(emb[i]);
  } else {
    int j = i - NNODES * 64;
    if (j < 32768){
      int jj = j >> 6, k = j & 63;
      float v = (jj < 256) ? W1[k * 256 + jj] : W1[(k + 64) * 256 + (jj - 256)];
      w1tn[j] = f2bf(v);
    } else {
      int jj = j - 32768;
      if (jj < 16384){
        int n = jj >> 8, k = jj & 255;
        w2t[jj] = f2bf(W2[k * 64 + n]);
      }
    }
  }
}

// ---------------- merged hists: per-graph counts (LDS-privatized) + per-col counts ----------------
__global__ void hists(const int* __restrict__ ei, const int* __restrict__ batch,
                      unsigned* __restrict__ hist, unsigned* __restrict__ chist){
  __shared__ unsigned h[NG];
  int t = threadIdx.x;
  h[t] = 0; h[t + 256] = 0;
  __syncthreads();
  for (int i = 0; i < 4; i++){
    int e = blockIdx.x * 1024 + i * 256 + t;
    if (e < EDGES){
      int cn = ei[e];
      atomicAdd(&chist[cn], 1u);
      atomicAdd(&h[batch[cn]], 1u);
    }
  }
  __syncthreads();
  atomicAdd(&hist[t], h[t]);
  atomicAdd(&hist[t + 256], h[t + 256]);
}

__global__ void col_scan1(const unsigned* __restrict__ chist, unsigned* __restrict__ cpre,
                          unsigned* __restrict__ bsum){
  __shared__ unsigned s[256];
  int t = threadIdx.x;
  int i = blockIdx.x * 256 + t;
  unsigned v = (i < NNODES) ? chist[i] : 0u;
  s[t] = v;
  __syncthreads();
  for (int o = 1; o < 256; o <<= 1){
    unsigned u = (t >= o) ? s[t - o] : 0u;
    __syncthreads();
    s[t] += u;
    __syncthreads();
  }
  cpre[i] = s[t] - v;                 // exclusive within block
  if (t == 255) bsum[blockIdx.x] = s[255];
}

__global__ void col_scan2(unsigned* __restrict__ bsum){   // 196 partials, 1 block
  __shared__ unsigned s[256];
  int t = threadIdx.x;
  unsigned v = (t < 196) ? bsum[t] : 0u;
  s[t] = v;
  __syncthreads();
  for (int o = 1; o < 256; o <<= 1){
    unsigned u = (t >= o) ? s[t - o] : 0u;
    __syncthreads();
    s[t] += u;
    __syncthreads();
  }
  if (t < 196) bsum[t] = s[t] - v;    // exclusive block offsets
}

__global__ void col_scan3(unsigned* __restrict__ cpre, const unsigned* __restrict__ bsum){
  int i = blockIdx.x * 256 + threadIdx.x;
  cpre[i] += bsum[blockIdx.x];
}

// emeta[pos] = (col, row, seg, orig_edge); cpre used as cursors (destructive)
__global__ void col_scatter(const int* __restrict__ ei, const int* __restrict__ batch,
                            unsigned* __restrict__ cpre, int4* __restrict__ emeta){
  for (int i = 0; i < 4; i++){
    int e = blockIdx.x * 1024 + i * 256 + threadIdx.x;
    if (e < EDGES){
      int cn = ei[e];
      int pos = (int)atomicAdd(&cpre[cn], 1u);
      emeta[pos] = make_int4(cn, ei[EDGES + e], batch[cn], e);
    }
  }
}

// ---------------- node GEMM: P[node][512] = emb @ [W1top | W1bot] ----------------
__global__ __launch_bounds__(256) void node_gemm(
    const unsigned short* __restrict__ emb_bf, const unsigned short* __restrict__ w1tn,
    unsigned short* __restrict__ P)
{
  __shared__ unsigned short As[64 * 72];   // 64 nodes x 64 k, +8 pad
  int t = threadIdx.x;
  int n0 = blockIdx.x * 64;
  {
    int nl = t >> 2, part = t & 3;
    int node = n0 + nl; if (node >= NNODES) node = 0;
    const int4* src = (const int4*)(emb_bf + node * 64 + part * 16);
    int4* dst = (int4*)(As + nl * 72 + part * 16);
    dst[0] = src[0]; dst[1] = src[1];
  }
  __syncthreads();
  int w = t >> 6, lane = t & 63, q = lane >> 4, c = lane & 15;
  f32x4 acc[4][8];
  for (int a = 0; a < 4; a++) for (int b = 0; b < 8; b++) for (int r = 0; r < 4; r++) acc[a][b][r] = 0.f;
  for (int k0 = 0; k0 < 64; k0 += 32){
    bf16x8 af[4];
    for (int tt = 0; tt < 4; tt++) af[tt] = *(const bf16x8*)(As + (tt * 16 + c) * 72 + k0 + q * 8);
    for (int n4 = 0; n4 < 8; n4++){
      bf16x8 bw = *(const bf16x8*)(w1tn + (w * 128 + n4 * 16 + c) * 64 + k0 + q * 8);
      for (int tt = 0; tt < 4; tt++)
        acc[tt][n4] = __builtin_amdgcn_mfma_f32_16x16x32_bf16(af[tt], bw, acc[tt][n4], 0, 0, 0);
    }
  }
  for (int tt = 0; tt < 4; tt++){
    for (int r = 0; r < 4; r++){
      int node = n0 + tt * 16 + q * 4 + r;
      if (node < NNODES){
        unsigned short* dst = P + (size_t)node * 512 + w * 128 + c;
        for (int n4 = 0; n4 < 8; n4++) dst[n4 * 16] = f2bf(acc[tt][n4][r]);
      }
    }
  }
}

// ---------------- K1: gather + segmented stats1 ----------------
// 8 tiles/block (512 edges), 2 tiles/wave; <=2 graphs per block (col-sorted).
// LDS 2-slot accumulation, one set of global atomics per block. (R1 form — best.)
__global__ __launch_bounds__(256, 5) void k1_gather(
    const unsigned short* __restrict__ P, const int4* __restrict__ emeta,
    float* __restrict__ sum1, float* __restrict__ sqs1)
{
  __shared__ float ls[1024];   // [slot:2][sum/sqs:2][ch:256]
  int t = threadIdx.x;
  int bid = xcd_swizzle(blockIdx.x, gridDim.x);
  int tile0 = bid * 8;
  for (int i = t; i < 1024; i += 256) ls[i] = 0.f;
  int s0 = emeta[tile0 * 64].z;
  int elast = tile0 * 64 + 511; if (elast >= EDGES) elast = EDGES - 1;
  int s1 = emeta[elast].z;
  __syncthreads();

  int w = t >> 6, lane = t & 63, c4 = lane * 4;

  float sm0 = 0.f, sm1 = 0.f, sm2 = 0.f, sm3 = 0.f;
  float q0 = 0.f, q1 = 0.f, q2 = 0.f, q3 = 0.f;
  int curs = -1;   // seg currently held in the register accumulators

  auto FLUSH = [&](int s){
    if (s == s0 || s == s1){
      float* base = ls + ((s == s0) ? 0 : 512) + c4;
      atomicAdd(base + 0, sm0); atomicAdd(base + 1, sm1);
      atomicAdd(base + 2, sm2); atomicAdd(base + 3, sm3);
      atomicAdd(base + 256, q0); atomicAdd(base + 257, q1);
      atomicAdd(base + 258, q2); atomicAdd(base + 259, q3);
    } else {  // safety net: >2 segs in block (practically impossible)
      float* sp = sum1 + s * 256 + c4;
      float* qp = sqs1 + s * 256 + c4;
      atomicAdd(sp + 0, sm0); atomicAdd(sp + 1, sm1); atomicAdd(sp + 2, sm2); atomicAdd(sp + 3, sm3);
      atomicAdd(qp + 0, q0);  atomicAdd(qp + 1, q1);  atomicAdd(qp + 2, q2);  atomicAdd(qp + 3, q3);
    }
    sm0 = sm1 = sm2 = sm3 = 0.f; q0 = q1 = q2 = q3 = 0.f;
  };

  for (int ti = 0; ti < 2; ti++){
    int tile = tile0 + w * 2 + ti;
    if (tile >= NTILES) continue;
    int4 me = emeta[tile * 64 + lane];
    int sseg = __builtin_amdgcn_readlane(me.z, 0);
    bool uni = (__ballot(me.z == sseg) == ~0ull);
    if (uni){
      if (sseg != curs){
        if (curs >= 0) FLUSH(curs);
        curs = sseg;
      }
      // rolling prefetch: 3 groups of 4 edges in flight (rows + cols)
      ushort4 rv[3][4], cv[3][4];
      #pragma unroll
      for (int g = 0; g < 2; g++){
        #pragma unroll
        for (int j = 0; j < 4; j++){
          int e = g * 4 + j;
          int re = __builtin_amdgcn_readlane(me.y, e);
          int ce = __builtin_amdgcn_readlane(me.x, e);
          rv[g][j] = *(const ushort4*)(P + (size_t)re * 512 + 256 + c4);
          cv[g][j] = *(const ushort4*)(P + (size_t)ce * 512 + c4);
        }
      }
      #pragma unroll
      for (int g = 0; g < 16; g++){
        if (g < 14){
          int bn = (g + 2) % 3;
          #pragma unroll
          for (int j = 0; j < 4; j++){
            int e = (g + 2) * 4 + j;
            int re = __builtin_amdgcn_readlane(me.y, e);
            int ce = __builtin_amdgcn_readlane(me.x, e);
            rv[bn][j] = *(const ushort4*)(P + (size_t)re * 512 + 256 + c4);
            cv[bn][j] = *(const ushort4*)(P + (size_t)ce * 512 + c4);
          }
        }
        int b = g % 3;
        #pragma unroll
        for (int j = 0; j < 4; j++){
          float x0 = bf2f(cv[b][j].x) + bf2f(rv[b][j].x);
          float x1 = bf2f(cv[b][j].y) + bf2f(rv[b][j].y);
          float x2v = bf2f(cv[b][j].z) + bf2f(rv[b][j].z);
          float x3 = bf2f(cv[b][j].w) + bf2f(rv[b][j].w);
          sm0 += x0; q0 += x0 * x0;
          sm1 += x1; q1 += x1 * x1;
          sm2 += x2v; q2 += x2v * x2v;
          sm3 += x3; q3 += x3 * x3;
        }
      }
    } else {
      // rare (~3% of tiles): seg changes inside the tile — serial path
      int cprev = -1;
      ushort4 a = make_ushort4(0, 0, 0, 0);
      for (int e = 0; e < 64; e++){
        int ce = __builtin_amdgcn_readlane(me.x, e);
        int re = __builtin_amdgcn_readlane(me.y, e);
        int s = __builtin_amdgcn_readlane(me.z, e);
        if (s != curs){
          if (curs >= 0) FLUSH(curs);
          curs = s;
        }
        if (ce != cprev){ a = *(const ushort4*)(P + (size_t)ce * 512 + c4); cprev = ce; }
        ushort4 b = *(const ushort4*)(P + (size_t)re * 512 + 256 + c4);
        float x0 = bf2f(a.x) + bf2f(b.x);
        float x1 = bf2f(a.y) + bf2f(b.y);
        float x2v = bf2f(a.z) + bf2f(b.z);
        float x3 = bf2f(a.w) + bf2f(b.w);
        sm0 += x0; q0 += x0 * x0;
        sm1 += x1; q1 += x1 * x1;
        sm2 += x2v; q2 += x2v * x2v;
        sm3 += x3; q3 += x3 * x3;
      }
    }
  }
  if (curs >= 0) FLUSH(curs);

  __syncthreads();
  // block-level emit: thread t owns channel t
  atomicAdd(&sum1[s0 * 256 + t], ls[t]);
  atomicAdd(&sqs1[s0 * 256 + t], ls[256 + t]);
  if (s1 != s0){
    atomicAdd(&sum1[s1 * 256 + t], ls[512 + t]);
    atomicAdd(&sqs1[s1 * 256 + t], ls[768 + t]);
  }
}

// ---------------- finalize: emit rstd and mean*rstd ----------------
__global__ void finalize1(const float* __restrict__ sum1, const float* __restrict__ sqs1,
                          const unsigned* __restrict__ hist, float* __restrict__ r1,
                          float* __restrict__ mr1){
  int i = blockIdx.x * 256 + threadIdx.x;   // 512*256
  int g = i >> 8;
  float cnt = fmaxf((float)hist[g], 1.f);
  float m = sum1[i] / cnt;
  float v = sqs1[i] / cnt - m * m;
  v = fmaxf(v, 0.f);
  float r = rsqrtf(v + 1e-5f);
  r1[i] = r;
  mr1[i] = m * r;
}

__global__ void finalize2(const float* __restrict__ sum2, const float* __restrict__ sqs2,
                          const unsigned* __restrict__ hist, float* __restrict__ r2,
                          float* __restrict__ mr2){
  int i = blockIdx.x * 256 + threadIdx.x;   // 512*64
  int g = i >> 6;
  float cnt = fmaxf((float)hist[g], 1.f);
  float m = sum2[i] / cnt;
  float v = sqs2[i] / cnt - m * m;
  v = fmaxf(v, 0.f);
  float r = rsqrtf(v + 1e-5f);
  r2[i] = r;
  mr2[i] = m * r;
}

// ---------------- K2: all-register gather -> norm/relu -> GEMM2 + stats2 + x2T ----------------
// R6 restructure. Facts: 155us across 3 staging schemes; 2x occupancy made it
// WORSE (R5); VALUBusy ~50%, LDS pipe carries ~224KB/block + 2 full barriers.
// New design exploits the MFMA A-fragment layout: lane (c,q) of a 16x16x32
// MFMA holds A[row=c][k=q*8+kc*32]. So: wave w owns 16 edges; lane's edge is
// c (me = emeta[p0+w*16+c], per-lane — NO readlane dedup chains); lane gathers
// P[col_c][ch], P[row_c][256+ch] for ch=kc*32+q*8..+8, applies norm/relu in
// registers, and the result IS the A-fragment. B = w2t fragments (L1-hot).
// => zero LDS, zero barriers, fully independent waves; nothing for the
// allocator to sink past (the R2/R3 failure), normal load hoisting applies.
__global__ __launch_bounds__(256, 4) void k2_fused(
    const unsigned short* __restrict__ P, const unsigned short* __restrict__ w2t,
    const int4* __restrict__ emeta,
    const float* __restrict__ r1, const float* __restrict__ mr1,
    float* __restrict__ sum2, float* __restrict__ sqs2,
    unsigned short* __restrict__ x2t)
{
  int t = threadIdx.x;
  int bid = xcd_swizzle(blockIdx.x, gridDim.x);
  int p0 = bid * 64;
  int w = t >> 6, lane = t & 63, q = lane >> 4, c = lane & 15;
  int e0 = w * 16;
  int4 me = emeta[p0 + e0 + c];   // lane's edge = c; fields are per-lane

  const unsigned short* colp = P + (size_t)me.x * 512;
  const unsigned short* rowp = P + (size_t)me.y * 512 + 256;
  const float* rp = r1  + me.z * 256;
  const float* mp = mr1 + me.z * 256;

  f32x4 acc2[4];
  #pragma unroll
  for (int ng = 0; ng < 4; ng++)
    #pragma unroll
    for (int r = 0; r < 4; r++) acc2[ng][r] = 0.f;

  #pragma unroll
  for (int kc = 0; kc < 8; kc++){
    int ch0 = kc * 32 + q * 8;
    union { int4 i; unsigned short u[8]; } ua, ub;
    ua.i = *(const int4*)(colp + ch0);
    ub.i = *(const int4*)(rowp + ch0);
    float4 rlo = *(const float4*)(rp + ch0);
    float4 rhi = *(const float4*)(rp + ch0 + 4);
    float4 mlo = *(const float4*)(mp + ch0);
    float4 mhi = *(const float4*)(mp + ch0 + 4);
    float y0 = fmaxf(0.f, (bf2f(ua.u[0]) + bf2f(ub.u[0])) * rlo.x - mlo.x);
    float y1 = fmaxf(0.f, (bf2f(ua.u[1]) + bf2f(ub.u[1])) * rlo.y - mlo.y);
    float y2 = fmaxf(0.f, (bf2f(ua.u[2]) + bf2f(ub.u[2])) * rlo.z - mlo.z);
    float y3 = fmaxf(0.f, (bf2f(ua.u[3]) + bf2f(ub.u[3])) * rlo.w - mlo.w);
    float y4 = fmaxf(0.f, (bf2f(ua.u[4]) + bf2f(ub.u[4])) * rhi.x - mhi.x);
    float y5 = fmaxf(0.f, (bf2f(ua.u[5]) + bf2f(ub.u[5])) * rhi.y - mhi.y);
    float y6 = fmaxf(0.f, (bf2f(ua.u[6]) + bf2f(ub.u[6])) * rhi.z - mhi.z);
    float y7 = fmaxf(0.f, (bf2f(ua.u[7]) + bf2f(ub.u[7])) * rhi.w - mhi.w);
    union { bf16x8 v; unsigned u[4]; } af;
    af.u[0] = pk2bf(y0, y1);
    af.u[1] = pk2bf(y2, y3);
    af.u[2] = pk2bf(y4, y5);
    af.u[3] = pk2bf(y6, y7);
    #pragma unroll
    for (int ng = 0; ng < 4; ng++){
      bf16x8 bfr = *(const bf16x8*)(w2t + (ng * 16 + c) * 256 + ch0);
      acc2[ng] = __builtin_amdgcn_mfma_f32_16x16x32_bf16(af.v, bfr, acc2[ng], 0, 0, 0);
    }
  }

  // stats2 over this wave's 16 edges. D layout: acc2[ng][r] = edge q*4+r,
  // channel ng*16+c.
  int s0 = __builtin_amdgcn_readlane(me.z, 0);
  bool uni = (__ballot(me.z == s0) == ~0ull);
  if (uni){
    #pragma unroll
    for (int ng = 0; ng < 4; ng++){
      float sm = acc2[ng][0] + acc2[ng][1] + acc2[ng][2] + acc2[ng][3];
      float sq = acc2[ng][0] * acc2[ng][0] + acc2[ng][1] * acc2[ng][1]
               + acc2[ng][2] * acc2[ng][2] + acc2[ng][3] * acc2[ng][3];
      sm += __shfl_xor(sm, 16); sq += __shfl_xor(sq, 16);
      sm += __shfl_xor(sm, 32); sq += __shfl_xor(sq, 32);
      if (q == 0){
        atomicAdd(&sum2[s0 * 64 + ng * 16 + c], sm);
        atomicAdd(&sqs2[s0 * 64 + ng * 16 + c], sq);
      }
    }
  } else {
    // run decomposition over the 16 edges via ballot (lanes 0..15 carry segs)
    int prz = __shfl(me.z, (c == 0) ? 0 : (c - 1));
    unsigned long long bm = __ballot((lane < 16) && (c > 0) && (me.z != prz));
    int lo = 0;
    while (true){
      int hi = bm ? (int)__builtin_ctzll(bm) : 16;
      int s = __builtin_amdgcn_readlane(me.z, lo);
      #pragma unroll
      for (int ng = 0; ng < 4; ng++){
        float sm = 0.f, sq = 0.f;
        #pragma unroll
        for (int r = 0; r < 4; r++){
          int el = q * 4 + r;
          if (el >= lo && el < hi){ float v = acc2[ng][r]; sm += v; sq += v * v; }
        }
        sm += __shfl_xor(sm, 16); sq += __shfl_xor(sq, 16);
        sm += __shfl_xor(sm, 32); sq += __shfl_xor(sq, 32);
        if (q == 0){
          atomicAdd(&sum2[s * 64 + ng * 16 + c], sm);
          atomicAdd(&sqs2[s * 64 + ng * 16 + c], sq);
        }
      }
      if (!bm) break;
      lo = hi;
      bm &= bm - 1;
    }
  }

  // x2T store: channel ng*16+c, edges p0+e0+q*4..+4 (bf16 pairs)
  #pragma unroll
  for (int ng = 0; ng < 4; ng++){
    uint2 pk;
    pk.x = pk2bf(acc2[ng][0], acc2[ng][1]);
    pk.y = pk2bf(acc2[ng][2], acc2[ng][3]);
    *(uint2*)(x2t + (size_t)(ng * 16 + c) * EDGES + p0 + e0 + q * 4) = pk;
  }
}

// ---------------- K3: normalize2 + GEMV W3, 4 edges/thread (x2t is [ch][edge]) ----------------
__global__ __launch_bounds__(256) void k3_out(
    const unsigned short* __restrict__ x2t, const int4* __restrict__ emeta,
    const float* __restrict__ r2, const float* __restrict__ mr2,
    const float* __restrict__ W3, const float* __restrict__ b3, float* __restrict__ out)
{
  int pp4 = (blockIdx.x * 256 + threadIdx.x) * 4;
  if (pp4 >= EDGES) return;
  int4 m0 = emeta[pp4 + 0];
  int4 m1 = emeta[pp4 + 1];
  int4 m2 = emeta[pp4 + 2];
  int4 m3 = emeta[pp4 + 3];
  float a0 = 0.f, a1 = 0.f, a2 = 0.f, a3 = 0.f;
  if (m0.z == m3.z && m0.z == m1.z && m0.z == m2.z){
    const float* rp = r2  + m0.z * 64;
    const float* mp = mr2 + m0.z * 64;
    #pragma unroll 8
    for (int ch = 0; ch < 64; ch++){
      ushort4 v = *(const ushort4*)(x2t + (size_t)ch * EDGES + pp4);
      float rr = rp[ch], mm = mp[ch], wv = W3[ch];
      a0 += fmaxf(0.f, bf2f(v.x) * rr - mm) * wv;
      a1 += fmaxf(0.f, bf2f(v.y) * rr - mm) * wv;
      a2 += fmaxf(0.f, bf2f(v.z) * rr - mm) * wv;
      a3 += fmaxf(0.f, bf2f(v.w) * rr - mm) * wv;
    }
  } else {
    #pragma unroll 8
    for (int ch = 0; ch < 64; ch++){
      ushort4 v = *(const ushort4*)(x2t + (size_t)ch * EDGES + pp4);
      float wv = W3[ch];
      a0 += fmaxf(0.f, bf2f(v.x) * r2[m0.z * 64 + ch] - mr2[m0.z * 64 + ch]) * wv;
      a1 += fmaxf(0.f, bf2f(v.y) * r2[m1.z * 64 + ch] - mr2[m1.z * 64 + ch]) * wv;
      a2 += fmaxf(0.f, bf2f(v.z) * r2[m2.z * 64 + ch] - mr2[m2.z * 64 + ch]) * wv;
      a3 += fmaxf(0.f, bf2f(v.w) * r2[m3.z * 64 + ch] - mr2[m3.z * 64 + ch]) * wv;
    }
  }
  float bv = b3[0];
  out[m0.w] = a0 + bv;
  out[m1.w] = a1 + bv;
  out[m2.w] = a2 + bv;
  out[m3.w] = a3 + bv;
}

// ---------------- launch ----------------
extern "C" void kernel_launch(void* const* d_in, const int* in_sizes, int n_in,
                              void* d_out, int out_size, void* d_ws, size_t ws_size,
                              hipStream_t stream)
{
  (void)in_sizes; (void)n_in; (void)out_size;
  const float* emb = (const float*)d_in[0];
  const float* W1  = (const float*)d_in[1];
  const float* W2  = (const float*)d_in[3];
  const float* W3  = (const float*)d_in[5];
  const float* b3  = (const float*)d_in[6];
  const int* ei    = (const int*)d_in[7];
  const int* batch = (const int*)d_in[8];
  float* out = (float*)d_out;

  char* p = (char*)d_ws;
  size_t off = 0;
  auto take = [&](size_t n) -> char* {
    char* r = p + off;
    off += (n + 255) & ~(size_t)255;
    return r;
  };

  unsigned short* emb_bf = (unsigned short*)take((size_t)NNODES * 64 * 2);
  unsigned short* w1tn   = (unsigned short*)take(32768 * 2);
  unsigned short* w2t    = (unsigned short*)take(16384 * 2);
  int4* emeta = (int4*)take((size_t)EDGES * 16);
  unsigned short* P   = (unsigned short*)take((size_t)NNODES * 512 * 2);
  unsigned short* x2t = (unsigned short*)take((size_t)EDGES * 64 * 2);
  float* r1  = (float*)take(512 * 256 * 4);
  float* mr1 = (float*)take(512 * 256 * 4);
  float* r2  = (float*)take(512 * 64 * 4);
  float* mr2 = (float*)take(512 * 64 * 4);
  unsigned* cpre = (unsigned*)take(NCOLB * 4);
  unsigned* bsum = (unsigned*)take(256 * 4);
  // zero-init region (contiguous)
  char* zbase = p + off;
  unsigned* hist  = (unsigned*)take(NG * 4);
  unsigned* chist = (unsigned*)take(NCOLB * 4);
  float* sum1 = (float*)take(512 * 256 * 4);
  float* sqs1 = (float*)take(512 * 256 * 4);
  float* sum2 = (float*)take(512 * 64 * 4);
  float* sqs2 = (float*)take(512 * 64 * 4);
  size_t zsize = (size_t)((p + off) - zbase);

  if (ws_size < off) return;  // workspace too small — fail loudly via poison

  hipMemsetAsync(zbase, 0, zsize, stream);
  prep_all<<<12692, 256, 0, stream>>>(emb, W1, W2, emb_bf, w1tn, w2t);
  hists<<<977, 256, 0, stream>>>(ei, batch, hist, chist);
  col_scan1<<<196, 256, 0, stream>>>(chist, cpre, bsum);
  col_scan2<<<1, 256, 0, stream>>>(bsum);
  col_scan3<<<196, 256, 0, stream>>>(cpre, bsum);
  col_scatter<<<977, 256, 0, stream>>>(ei, batch, cpre, emeta);
  node_gemm<<<(NNODES + 63) / 64, 256, 0, stream>>>(emb_bf, w1tn, P);
  k1_gather<<<(NTILES + 7) / 8, 256, 0, stream>>>(P, emeta, sum1, sqs1);
  finalize1<<<512, 256, 0, stream>>>(sum1, sqs1, hist, r1, mr1);
  k2_fused<<<NTILES, 256, 0, stream>>>(P, w2t, emeta, r1, mr1, sum2, sqs2, x2t);
  finalize2<<<128, 256, 0, stream>>>(sum2, sqs2, hist, r2, mr2);
  k3_out<<<977, 256, 0, stream>>>(x2t, emeta, r2, mr2, W3, b3, out);
}

// Round 8
// 495.527 us; speedup vs baseline: 1.5432x; 1.5432x over previous
//
#include <hip/hip_runtime.h>
#include <hip/hip_bf16.h>

#define EDGES 1000000
#define NNODES 50000
#define NG 512
#define NTILES 15625  // EDGES/64
#define NCOLB 50176   // col-hist bins rounded to 196*256

typedef __attribute__((ext_vector_type(8))) short bf16x8;
typedef __attribute__((ext_vector_type(4))) float f32x4;

__device__ __forceinline__ unsigned short f2bf(float f){
  unsigned u = __float_as_uint(f);
  u += 0x7fffu + ((u >> 16) & 1u);
  return (unsigned short)(u >> 16);
}
__device__ __forceinline__ float bf2f(unsigned short h){
  return __uint_as_float(((unsigned)h) << 16);
}
__device__ __forceinline__ unsigned pk2bf(float x, float y){
  __hip_bfloat162 h = __float22bfloat162_rn(make_float2(x, y));
  union { __hip_bfloat162 h; unsigned u; } cv; cv.h = h;
  return cv.u;
}
// fire-and-forget global->LDS DMA, 16B per lane, dest = uniform base + lane*16
__device__ __forceinline__ void gload_lds16(const void* g, void* l){
  __builtin_amdgcn_global_load_lds(
      (const __attribute__((address_space(1))) unsigned int*)g,
      (__attribute__((address_space(3))) unsigned int*)l, 16, 0, 0);
}
// XCD-aware swizzle: contiguous tile ranges per XCD. TRUE BIJECTION.
__device__ __forceinline__ int xcd_swizzle(int bid, int nb){
  int nb8 = nb & ~7;
  if (bid >= nb8) return bid;
  int per = nb8 >> 3;
  return (bid & 7) * per + (bid >> 3);
}

// ---------------- prep: emb->bf16, W1->w1tn, W2->w2t ----------------
// R8: w2t k-index is in P-POSITION space. node_gemm stores position
// p = w*128 + c*8 + n4, which holds original channel
// pi(p) = (p&~127) | ((p&7)<<4) | ((p>>3)&15). All per-channel stats
// (sum1/r1/mr1) are position-wise (self-consistent under any fixed
// permutation); only W2's k-index must compensate: w2t[n*256+p] = W2[pi(p)][n].
__global__ void prep_all(const float* __restrict__ emb, const float* __restrict__ W1,
                         const float* __restrict__ W2,
                         unsigned short* __restrict__ emb_bf,
                         unsigned short* __restrict__ w1tn, unsigned short* __restrict__ w2t){
  int i = blockIdx.x * 256 + threadIdx.x;
  if (i < NNODES * 64){
    emb_bf[i] = f2bf(emb[i]);
  } else {
    int j = i - NNODES * 64;
    if (j < 32768){
      int jj = j >> 6, k = j & 63;
      float v = (jj < 256) ? W1[k * 256 + jj] : W1[(k + 64) * 256 + (jj - 256)];
      w1tn[j] = f2bf(v);
    } else {
      int jj = j - 32768;
      if (jj < 16384){
        int n = jj >> 8, p = jj & 255;
        int korig = (p & ~127) | ((p & 7) << 4) | ((p >> 3) & 15);
        w2t[jj] = f2bf(W2[korig * 64 + n]);
      }
    }
  }
}

// ---------------- merged hists: per-graph counts (LDS-privatized) + per-col counts ----------------
__global__ void hists(const int* __restrict__ ei, const int* __restrict__ batch,
                      unsigned* __restrict__ hist, unsigned* __restrict__ chist){
  __shared__ unsigned h[NG];
  int t = threadIdx.x;
  h[t] = 0; h[t + 256] = 0;
  __syncthreads();
  for (int i = 0; i < 4; i++){
    int e = blockIdx.x * 1024 + i * 256 + t;
    if (e < EDGES){
      int cn = ei[e];
      atomicAdd(&chist[cn], 1u);
      atomicAdd(&h[batch[cn]], 1u);
    }
  }
  __syncthreads();
  atomicAdd(&hist[t], h[t]);
  atomicAdd(&hist[t + 256], h[t + 256]);
}

__global__ void col_scan1(const unsigned* __restrict__ chist, unsigned* __restrict__ cpre,
                          unsigned* __restrict__ bsum){
  __shared__ unsigned s[256];
  int t = threadIdx.x;
  int i = blockIdx.x * 256 + t;
  unsigned v = (i < NNODES) ? chist[i] : 0u;
  s[t] = v;
  __syncthreads();
  for (int o = 1; o < 256; o <<= 1){
    unsigned u = (t >= o) ? s[t - o] : 0u;
    __syncthreads();
    s[t] += u;
    __syncthreads();
  }
  cpre[i] = s[t] - v;                 // exclusive within block
  if (t == 255) bsum[blockIdx.x] = s[255];
}

__global__ void col_scan2(unsigned* __restrict__ bsum){   // 196 partials, 1 block
  __shared__ unsigned s[256];
  int t = threadIdx.x;
  unsigned v = (t < 196) ? bsum[t] : 0u;
  s[t] = v;
  __syncthreads();
  for (int o = 1; o < 256; o <<= 1){
    unsigned u = (t >= o) ? s[t - o] : 0u;
    __syncthreads();
    s[t] += u;
    __syncthreads();
  }
  if (t < 196) bsum[t] = s[t] - v;    // exclusive block offsets
}

__global__ void col_scan3(unsigned* __restrict__ cpre, const unsigned* __restrict__ bsum){
  int i = blockIdx.x * 256 + threadIdx.x;
  cpre[i] += bsum[blockIdx.x];
}

// emeta[pos] = (col, row, seg, orig_edge); cpre used as cursors (destructive)
__global__ void col_scatter(const int* __restrict__ ei, const int* __restrict__ batch,
                            unsigned* __restrict__ cpre, int4* __restrict__ emeta){
  for (int i = 0; i < 4; i++){
    int e = blockIdx.x * 1024 + i * 256 + threadIdx.x;
    if (e < EDGES){
      int cn = ei[e];
      int pos = (int)atomicAdd(&cpre[cn], 1u);
      emeta[pos] = make_int4(cn, ei[EDGES + e], batch[cn], e);
    }
  }
}

// ---------------- node GEMM: P[node][512] = emb @ [W1top | W1bot] ----------------
// R8: packed epilogue. Lane (c,q) holds acc[tt][n4][r] = orig channel
// w*128 + n4*16 + c of node tt*16+q*4+r. Store it at POSITION
// p = w*128 + c*8 + n4: the 8 n4 values are 16B contiguous -> one uint4
// store (16 stores/wave vs 128 scalar 2B stores). w2t is permuted to match.
__global__ __launch_bounds__(256) void node_gemm(
    const unsigned short* __restrict__ emb_bf, const unsigned short* __restrict__ w1tn,
    unsigned short* __restrict__ P)
{
  __shared__ unsigned short As[64 * 72];   // 64 nodes x 64 k, +8 pad
  int t = threadIdx.x;
  int n0 = blockIdx.x * 64;
  {
    int nl = t >> 2, part = t & 3;
    int node = n0 + nl; if (node >= NNODES) node = 0;
    const int4* src = (const int4*)(emb_bf + node * 64 + part * 16);
    int4* dst = (int4*)(As + nl * 72 + part * 16);
    dst[0] = src[0]; dst[1] = src[1];
  }
  __syncthreads();
  int w = t >> 6, lane = t & 63, q = lane >> 4, c = lane & 15;
  f32x4 acc[4][8];
  for (int a = 0; a < 4; a++) for (int b = 0; b < 8; b++) for (int r = 0; r < 4; r++) acc[a][b][r] = 0.f;
  for (int k0 = 0; k0 < 64; k0 += 32){
    bf16x8 af[4];
    for (int tt = 0; tt < 4; tt++) af[tt] = *(const bf16x8*)(As + (tt * 16 + c) * 72 + k0 + q * 8);
    for (int n4 = 0; n4 < 8; n4++){
      bf16x8 bw = *(const bf16x8*)(w1tn + (w * 128 + n4 * 16 + c) * 64 + k0 + q * 8);
      for (int tt = 0; tt < 4; tt++)
        acc[tt][n4] = __builtin_amdgcn_mfma_f32_16x16x32_bf16(af[tt], bw, acc[tt][n4], 0, 0, 0);
    }
  }
  for (int tt = 0; tt < 4; tt++){
    for (int r = 0; r < 4; r++){
      int node = n0 + tt * 16 + q * 4 + r;
      if (node < NNODES){
        uint4 pk;
        pk.x = pk2bf(acc[tt][0][r], acc[tt][1][r]);
        pk.y = pk2bf(acc[tt][2][r], acc[tt][3][r]);
        pk.z = pk2bf(acc[tt][4][r], acc[tt][5][r]);
        pk.w = pk2bf(acc[tt][6][r], acc[tt][7][r]);
        *(uint4*)(P + (size_t)node * 512 + w * 128 + c * 8) = pk;
      }
    }
  }
}

// ---------------- K1: gather + segmented stats1 ----------------
// 8 tiles/block (512 edges), 2 tiles/wave; <=2 graphs per block (col-sorted).
// LDS 2-slot accumulation, one set of global atomics per block. (R1 form — best.)
// Channel indices here are P-POSITIONS (permuted space) — self-consistent.
__global__ __launch_bounds__(256, 5) void k1_gather(
    const unsigned short* __restrict__ P, const int4* __restrict__ emeta,
    float* __restrict__ sum1, float* __restrict__ sqs1)
{
  __shared__ float ls[1024];   // [slot:2][sum/sqs:2][ch:256]
  int t = threadIdx.x;
  int bid = xcd_swizzle(blockIdx.x, gridDim.x);
  int tile0 = bid * 8;
  for (int i = t; i < 1024; i += 256) ls[i] = 0.f;
  int s0 = emeta[tile0 * 64].z;
  int elast = tile0 * 64 + 511; if (elast >= EDGES) elast = EDGES - 1;
  int s1 = emeta[elast].z;
  __syncthreads();

  int w = t >> 6, lane = t & 63, c4 = lane * 4;

  float sm0 = 0.f, sm1 = 0.f, sm2 = 0.f, sm3 = 0.f;
  float q0 = 0.f, q1 = 0.f, q2 = 0.f, q3 = 0.f;
  int curs = -1;   // seg currently held in the register accumulators

  auto FLUSH = [&](int s){
    if (s == s0 || s == s1){
      float* base = ls + ((s == s0) ? 0 : 512) + c4;
      atomicAdd(base + 0, sm0); atomicAdd(base + 1, sm1);
      atomicAdd(base + 2, sm2); atomicAdd(base + 3, sm3);
      atomicAdd(base + 256, q0); atomicAdd(base + 257, q1);
      atomicAdd(base + 258, q2); atomicAdd(base + 259, q3);
    } else {  // safety net: >2 segs in block (practically impossible)
      float* sp = sum1 + s * 256 + c4;
      float* qp = sqs1 + s * 256 + c4;
      atomicAdd(sp + 0, sm0); atomicAdd(sp + 1, sm1); atomicAdd(sp + 2, sm2); atomicAdd(sp + 3, sm3);
      atomicAdd(qp + 0, q0);  atomicAdd(qp + 1, q1);  atomicAdd(qp + 2, q2);  atomicAdd(qp + 3, q3);
    }
    sm0 = sm1 = sm2 = sm3 = 0.f; q0 = q1 = q2 = q3 = 0.f;
  };

  for (int ti = 0; ti < 2; ti++){
    int tile = tile0 + w * 2 + ti;
    if (tile >= NTILES) continue;
    int4 me = emeta[tile * 64 + lane];
    int sseg = __builtin_amdgcn_readlane(me.z, 0);
    bool uni = (__ballot(me.z == sseg) == ~0ull);
    if (uni){
      if (sseg != curs){
        if (curs >= 0) FLUSH(curs);
        curs = sseg;
      }
      // rolling prefetch: 3 groups of 4 edges in flight (rows + cols)
      ushort4 rv[3][4], cv[3][4];
      #pragma unroll
      for (int g = 0; g < 2; g++){
        #pragma unroll
        for (int j = 0; j < 4; j++){
          int e = g * 4 + j;
          int re = __builtin_amdgcn_readlane(me.y, e);
          int ce = __builtin_amdgcn_readlane(me.x, e);
          rv[g][j] = *(const ushort4*)(P + (size_t)re * 512 + 256 + c4);
          cv[g][j] = *(const ushort4*)(P + (size_t)ce * 512 + c4);
        }
      }
      #pragma unroll
      for (int g = 0; g < 16; g++){
        if (g < 14){
          int bn = (g + 2) % 3;
          #pragma unroll
          for (int j = 0; j < 4; j++){
            int e = (g + 2) * 4 + j;
            int re = __builtin_amdgcn_readlane(me.y, e);
            int ce = __builtin_amdgcn_readlane(me.x, e);
            rv[bn][j] = *(const ushort4*)(P + (size_t)re * 512 + 256 + c4);
            cv[bn][j] = *(const ushort4*)(P + (size_t)ce * 512 + c4);
          }
        }
        int b = g % 3;
        #pragma unroll
        for (int j = 0; j < 4; j++){
          float x0 = bf2f(cv[b][j].x) + bf2f(rv[b][j].x);
          float x1 = bf2f(cv[b][j].y) + bf2f(rv[b][j].y);
          float x2v = bf2f(cv[b][j].z) + bf2f(rv[b][j].z);
          float x3 = bf2f(cv[b][j].w) + bf2f(rv[b][j].w);
          sm0 += x0; q0 += x0 * x0;
          sm1 += x1; q1 += x1 * x1;
          sm2 += x2v; q2 += x2v * x2v;
          sm3 += x3; q3 += x3 * x3;
        }
      }
    } else {
      // rare (~3% of tiles): seg changes inside the tile — serial path
      int cprev = -1;
      ushort4 a = make_ushort4(0, 0, 0, 0);
      for (int e = 0; e < 64; e++){
        int ce = __builtin_amdgcn_readlane(me.x, e);
        int re = __builtin_amdgcn_readlane(me.y, e);
        int s = __builtin_amdgcn_readlane(me.z, e);
        if (s != curs){
          if (curs >= 0) FLUSH(curs);
          curs = s;
        }
        if (ce != cprev){ a = *(const ushort4*)(P + (size_t)ce * 512 + c4); cprev = ce; }
        ushort4 b = *(const ushort4*)(P + (size_t)re * 512 + 256 + c4);
        float x0 = bf2f(a.x) + bf2f(b.x);
        float x1 = bf2f(a.y) + bf2f(b.y);
        float x2v = bf2f(a.z) + bf2f(b.z);
        float x3 = bf2f(a.w) + bf2f(b.w);
        sm0 += x0; q0 += x0 * x0;
        sm1 += x1; q1 += x1 * x1;
        sm2 += x2v; q2 += x2v * x2v;
        sm3 += x3; q3 += x3 * x3;
      }
    }
  }
  if (curs >= 0) FLUSH(curs);

  __syncthreads();
  // block-level emit: thread t owns channel t
  atomicAdd(&sum1[s0 * 256 + t], ls[t]);
  atomicAdd(&sqs1[s0 * 256 + t], ls[256 + t]);
  if (s1 != s0){
    atomicAdd(&sum1[s1 * 256 + t], ls[512 + t]);
    atomicAdd(&sqs1[s1 * 256 + t], ls[768 + t]);
  }
}

// ---------------- finalize: emit rstd and mean*rstd ----------------
__global__ void finalize1(const float* __restrict__ sum1, const float* __restrict__ sqs1,
                          const unsigned* __restrict__ hist, float* __restrict__ r1,
                          float* __restrict__ mr1){
  int i = blockIdx.x * 256 + threadIdx.x;   // 512*256
  int g = i >> 8;
  float cnt = fmaxf((float)hist[g], 1.f);
  float m = sum1[i] / cnt;
  float v = sqs1[i] / cnt - m * m;
  v = fmaxf(v, 0.f);
  float r = rsqrtf(v + 1e-5f);
  r1[i] = r;
  mr1[i] = m * r;
}

__global__ void finalize2(const float* __restrict__ sum2, const float* __restrict__ sqs2,
                          const unsigned* __restrict__ hist, float* __restrict__ r2,
                          float* __restrict__ mr2){
  int i = blockIdx.x * 256 + threadIdx.x;   // 512*64
  int g = i >> 6;
  float cnt = fmaxf((float)hist[g], 1.f);
  float m = sum2[i] / cnt;
  float v = sqs2[i] / cnt - m * m;
  v = fmaxf(v, 0.f);
  float r = rsqrtf(v + 1e-5f);
  r2[i] = r;
  mr2[i] = m * r;
}

// ---------------- K2: gather -> norm/relu -> GEMM2 + stats2 + x2T store ----------------
// R4 structure (best known, 155us): rows staged via global_load_lds (8
// fire-and-forget 16B DMAs/wave), norm reads raw rows from LDS, writes back
// swizzled in-place; cols via the sorted demand-chain; GEMM2 reads Y with
// matching XOR swizzle. w2t is permuted to position-space (see prep).
__global__ __launch_bounds__(256, 4) void k2_fused(
    const unsigned short* __restrict__ P, const unsigned short* __restrict__ w2t,
    const int4* __restrict__ emeta,
    const float* __restrict__ r1, const float* __restrict__ mr1,
    float* __restrict__ sum2, float* __restrict__ sqs2,
    unsigned short* __restrict__ x2t)
{
  __shared__ unsigned short Y[64 * 256];   // raw rows staged linear, then swizzled y1
  __shared__ int segl[64];
  __shared__ short rsegA[64];
  __shared__ unsigned char rloA[65];
  __shared__ int nrunS;
  int t = threadIdx.x;
  int bid = xcd_swizzle(blockIdx.x, gridDim.x);
  int p0 = bid * 64;
  int w = t >> 6, lane = t & 63, q = lane >> 4, c = lane & 15;
  int c4 = lane * 4;
  int elb0 = w * 16;
  int4 me = emeta[p0 + elb0 + (lane & 15)];

  // stage this wave's 16 raw row-halves into Y rows [elb0, elb0+16), linear
  #pragma unroll
  for (int pp = 0; pp < 8; pp++){
    int r0 = __builtin_amdgcn_readlane(me.y, 2 * pp);
    int r1n = __builtin_amdgcn_readlane(me.y, 2 * pp + 1);
    int node = (lane < 32) ? r0 : r1n;
    const unsigned short* g = P + (size_t)node * 512 + 256 + (lane & 31) * 8;
    gload_lds16(g, &Y[(elb0 + 2 * pp) * 256]);
  }

  // issue first col row + norm factors while the DMAs fly
  int cprev = __builtin_amdgcn_readlane(me.x, 0);
  ushort4 a = *(const ushort4*)(P + (size_t)cprev * 512 + c4);
  int s0g = __builtin_amdgcn_readlane(me.z, 0);
  float4 r4  = *(const float4*)(r1  + s0g * 256 + c4);
  float4 mr4 = *(const float4*)(mr1 + s0g * 256 + c4);

  if (t < 64) segl[t] = emeta[p0 + t].z;
  if (w == 0){
    int sN = segl[lane];
    int nxt = (lane < 63) ? segl[lane + 1] : sN;
    unsigned long long mask = __ballot(sN != nxt);
    if (lane == 0){
      if (mask == 0ull){
        nrunS = 1; rloA[0] = 0; rloA[1] = 64; rsegA[0] = (short)sN;
      } else {
        int n = 0, cur = segl[0];
        rsegA[0] = (short)cur; rloA[0] = 0;
        for (int i = 1; i < 64; i++)
          if (segl[i] != cur){ cur = segl[i]; n++; rsegA[n] = (short)cur; rloA[n] = (unsigned char)i; }
        rloA[n + 1] = 64; nrunS = n + 1;
      }
    }
  }
  __syncthreads();   // drains vmcnt(0): all staged rows are in LDS past here
  int nrun = nrunS;
  bool uni = (nrun == 1);

  // read all 16 raw rows (LDS, 2-way-conflict-free), then norm+swizzled write
  ushort4 bb[16];
  #pragma unroll
  for (int e = 0; e < 16; e++)
    bb[e] = *(const ushort4*)(Y + (elb0 + e) * 256 + c4);

  #pragma unroll
  for (int e = 0; e < 16; e++){
    int ce = __builtin_amdgcn_readlane(me.x, e);
    if (ce != cprev){ a = *(const ushort4*)(P + (size_t)ce * 512 + c4); cprev = ce; }
    float4 rr4 = r4, mm4 = mr4;
    if (!uni){
      int s = __builtin_amdgcn_readlane(me.z, e);
      rr4 = *(const float4*)(r1  + s * 256 + c4);
      mm4 = *(const float4*)(mr1 + s * 256 + c4);
    }
    float y0 = fmaxf(0.f, (bf2f(a.x) + bf2f(bb[e].x)) * rr4.x - mm4.x);
    float y1 = fmaxf(0.f, (bf2f(a.y) + bf2f(bb[e].y)) * rr4.y - mm4.y);
    float y2 = fmaxf(0.f, (bf2f(a.z) + bf2f(bb[e].z)) * rr4.z - mm4.z);
    float y3 = fmaxf(0.f, (bf2f(a.w) + bf2f(bb[e].w)) * rr4.w - mm4.w);
    uint2 pk;
    pk.x = pk2bf(y0, y1);
    pk.y = pk2bf(y2, y3);
    int row = elb0 + e;
    // swizzled in-place write: bijective permutation of the row's 512B
    *(uint2*)((char*)Y + row * 512 + ((lane * 8) ^ ((row & 7) << 4))) = pk;
  }
  __syncthreads();

  // GEMM2: wave w owns out-channels [w*16, w*16+16)
  f32x4 acc2[4];
  for (int tt = 0; tt < 4; tt++) for (int r = 0; r < 4; r++) acc2[tt][r] = 0.f;
  int ch2 = w * 16 + c;
  int swzr = (c & 7) << 4;   // (row&7)<<4 with row = tt*16+c: low 3 bits from c only
  for (int kc = 0; kc < 8; kc++){
    bf16x8 bfr = *(const bf16x8*)(w2t + ch2 * 256 + kc * 32 + q * 8);
    int kb = (kc * 64 + q * 16) ^ swzr;   // byte offset within row, swizzled
    for (int tt = 0; tt < 4; tt++){
      bf16x8 afr = *(const bf16x8*)((const char*)Y + (tt * 16 + c) * 512 + kb);
      acc2[tt] = __builtin_amdgcn_mfma_f32_16x16x32_bf16(afr, bfr, acc2[tt], 0, 0, 0);
    }
  }

  if (uni){
    int s = segl[0];
    float sm = 0.f, sq = 0.f;
    for (int tt = 0; tt < 4; tt++)
      for (int r = 0; r < 4; r++){
        float v = acc2[tt][r];
        sm += v; sq += v * v;
      }
    sm += __shfl_xor(sm, 16); sq += __shfl_xor(sq, 16);
    sm += __shfl_xor(sm, 32); sq += __shfl_xor(sq, 32);
    if (q == 0){
      atomicAdd(&sum2[s * 64 + ch2], sm);
      atomicAdd(&sqs2[s * 64 + ch2], sq);
    }
  } else {
    for (int rr = 0; rr < nrun; rr++){
      int s = rsegA[rr], lo = rloA[rr], hi = rloA[rr + 1];
      float sm = 0.f, sq = 0.f;
      for (int tt = 0; tt < 4; tt++){
        int elb = tt * 16 + q * 4;
        for (int r = 0; r < 4; r++){
          int el = elb + r;
          if (el >= lo && el < hi){
            float v = acc2[tt][r];
            sm += v; sq += v * v;
          }
        }
      }
      sm += __shfl_xor(sm, 16); sq += __shfl_xor(sq, 16);
      sm += __shfl_xor(sm, 32); sq += __shfl_xor(sq, 32);
      if (q == 0){
        atomicAdd(&sum2[s * 64 + ch2], sm);
        atomicAdd(&sqs2[s * 64 + ch2], sq);
      }
    }
  }
  // x2T store: [ch][edge], ushort4 over 4 consecutive edges
  for (int tt = 0; tt < 4; tt++){
    uint2 pk;
    pk.x = pk2bf(acc2[tt][0], acc2[tt][1]);
    pk.y = pk2bf(acc2[tt][2], acc2[tt][3]);
    *(uint2*)(x2t + (size_t)ch2 * EDGES + p0 + tt * 16 + q * 4) = pk;
  }
}

// ---------------- K3: normalize2 + GEMV W3, 4 edges/thread (x2t is [ch][edge]) ----------------
__global__ __launch_bounds__(256) void k3_out(
    const unsigned short* __restrict__ x2t, const int4* __restrict__ emeta,
    const float* __restrict__ r2, const float* __restrict__ mr2,
    const float* __restrict__ W3, const float* __restrict__ b3, float* __restrict__ out)
{
  int pp4 = (blockIdx.x * 256 + threadIdx.x) * 4;
  if (pp4 >= EDGES) return;
  int4 m0 = emeta[pp4 + 0];
  int4 m1 = emeta[pp4 + 1];
  int4 m2 = emeta[pp4 + 2];
  int4 m3 = emeta[pp4 + 3];
  float a0 = 0.f, a1 = 0.f, a2 = 0.f, a3 = 0.f;
  if (m0.z == m3.z && m0.z == m1.z && m0.z == m2.z){
    const float* rp = r2  + m0.z * 64;
    const float* mp = mr2 + m0.z * 64;
    #pragma unroll 8
    for (int ch = 0; ch < 64; ch++){
      ushort4 v = *(const ushort4*)(x2t + (size_t)ch * EDGES + pp4);
      float rr = rp[ch], mm = mp[ch], wv = W3[ch];
      a0 += fmaxf(0.f, bf2f(v.x) * rr - mm) * wv;
      a1 += fmaxf(0.f, bf2f(v.y) * rr - mm) * wv;
      a2 += fmaxf(0.f, bf2f(v.z) * rr - mm) * wv;
      a3 += fmaxf(0.f, bf2f(v.w) * rr - mm) * wv;
    }
  } else {
    #pragma unroll 8
    for (int ch = 0; ch < 64; ch++){
      ushort4 v = *(const ushort4*)(x2t + (size_t)ch * EDGES + pp4);
      float wv = W3[ch];
      a0 += fmaxf(0.f, bf2f(v.x) * r2[m0.z * 64 + ch] - mr2[m0.z * 64 + ch]) * wv;
      a1 += fmaxf(0.f, bf2f(v.y) * r2[m1.z * 64 + ch] - mr2[m1.z * 64 + ch]) * wv;
      a2 += fmaxf(0.f, bf2f(v.z) * r2[m2.z * 64 + ch] - mr2[m2.z * 64 + ch]) * wv;
      a3 += fmaxf(0.f, bf2f(v.w) * r2[m3.z * 64 + ch] - mr2[m3.z * 64 + ch]) * wv;
    }
  }
  float bv = b3[0];
  out[m0.w] = a0 + bv;
  out[m1.w] = a1 + bv;
  out[m2.w] = a2 + bv;
  out[m3.w] = a3 + bv;
}

// ---------------- launch ----------------
extern "C" void kernel_launch(void* const* d_in, const int* in_sizes, int n_in,
                              void* d_out, int out_size, void* d_ws, size_t ws_size,
                              hipStream_t stream)
{
  (void)in_sizes; (void)n_in; (void)out_size;
  const float* emb = (const float*)d_in[0];
  const float* W1  = (const float*)d_in[1];
  const float* W2  = (const float*)d_in[3];
  const float* W3  = (const float*)d_in[5];
  const float* b3  = (const float*)d_in[6];
  const int* ei    = (const int*)d_in[7];
  const int* batch = (const int*)d_in[8];
  float* out = (float*)d_out;

  char* p = (char*)d_ws;
  size_t off = 0;
  auto take = [&](size_t n) -> char* {
    char* r = p + off;
    off += (n + 255) & ~(size_t)255;
    return r;
  };

  unsigned short* emb_bf = (unsigned short*)take((size_t)NNODES * 64 * 2);
  unsigned short* w1tn   = (unsigned short*)take(32768 * 2);
  unsigned short* w2t    = (unsigned short*)take(16384 * 2);
  int4* emeta = (int4*)take((size_t)EDGES * 16);
  unsigned short* P   = (unsigned short*)take((size_t)NNODES * 512 * 2);
  unsigned short* x2t = (unsigned short*)take((size_t)EDGES * 64 * 2);
  float* r1  = (float*)take(512 * 256 * 4);
  float* mr1 = (float*)take(512 * 256 * 4);
  float* r2  = (float*)take(512 * 64 * 4);
  float* mr2 = (float*)take(512 * 64 * 4);
  unsigned* cpre = (unsigned*)take(NCOLB * 4);
  unsigned* bsum = (unsigned*)take(256 * 4);
  // zero-init region (contiguous)
  char* zbase = p + off;
  unsigned* hist  = (unsigned*)take(NG * 4);
  unsigned* chist = (unsigned*)take(NCOLB * 4);
  float* sum1 = (float*)take(512 * 256 * 4);
  float* sqs1 = (float*)take(512 * 256 * 4);
  float* sum2 = (float*)take(512 * 64 * 4);
  float* sqs2 = (float*)take(512 * 64 * 4);
  size_t zsize = (size_t)((p + off) - zbase);

  if (ws_size < off) return;  // workspace too small — fail loudly via poison

  hipMemsetAsync(zbase, 0, zsize, stream);
  prep_all<<<12692, 256, 0, stream>>>(emb, W1, W2, emb_bf, w1tn, w2t);
  hists<<<977, 256, 0, stream>>>(ei, batch, hist, chist);
  col_scan1<<<196, 256, 0, stream>>>(chist, cpre, bsum);
  col_scan2<<<1, 256, 0, stream>>>(bsum);
  col_scan3<<<196, 256, 0, stream>>>(cpre, bsum);
  col_scatter<<<977, 256, 0, stream>>>(ei, batch, cpre, emeta);
  node_gemm<<<(NNODES + 63) / 64, 256, 0, stream>>>(emb_bf, w1tn, P);
  k1_gather<<<(NTILES + 7) / 8, 256, 0, stream>>>(P, emeta, sum1, sqs1);
  finalize1<<<512, 256, 0, stream>>>(sum1, sqs1, hist, r1, mr1);
  k2_fused<<<NTILES, 256, 0, stream>>>(P, w2t, emeta, r1, mr1, sum2, sqs2, x2t);
  finalize2<<<128, 256, 0, stream>>>(sum2, sqs2, hist, r2, mr2);
  k3_out<<<977, 256, 0, stream>>>(x2t, emeta, r2, mr2, W3, b3, out);
}

// Round 9
// 495.102 us; speedup vs baseline: 1.5446x; 1.0009x over previous
//
#include <hip/hip_runtime.h>
#include <hip/hip_bf16.h>

#define EDGES 1000000
#define NNODES 50000
#define NG 512
#define NTILES 15625  // EDGES/64
#define NCOLB 50176   // col-hist bins rounded to 196*256
#define HBLK 977      // hists/scatter block count (EDGES/1024 rounded up)
#define GBLK 782      // node_gemm block count (NNODES/64 rounded up)

typedef __attribute__((ext_vector_type(8))) short bf16x8;
typedef __attribute__((ext_vector_type(4))) float f32x4;

__device__ __forceinline__ unsigned short f2bf(float f){
  unsigned u = __float_as_uint(f);
  u += 0x7fffu + ((u >> 16) & 1u);
  return (unsigned short)(u >> 16);
}
__device__ __forceinline__ float bf2f(unsigned short h){
  return __uint_as_float(((unsigned)h) << 16);
}
__device__ __forceinline__ unsigned pk2bf(float x, float y){
  __hip_bfloat162 h = __float22bfloat162_rn(make_float2(x, y));
  union { __hip_bfloat162 h; unsigned u; } cv; cv.h = h;
  return cv.u;
}
// fire-and-forget global->LDS DMA, 16B per lane, dest = uniform base + lane*16
__device__ __forceinline__ void gload_lds16(const void* g, void* l){
  __builtin_amdgcn_global_load_lds(
      (const __attribute__((address_space(1))) unsigned int*)g,
      (__attribute__((address_space(3))) unsigned int*)l, 16, 0, 0);
}
// XCD-aware swizzle: contiguous tile ranges per XCD. TRUE BIJECTION.
__device__ __forceinline__ int xcd_swizzle(int bid, int nb){
  int nb8 = nb & ~7;
  if (bid >= nb8) return bid;
  int per = nb8 >> 3;
  return (bid & 7) * per + (bid >> 3);
}

// ---------------- merged: hists (blocks 0..976) + prep (blocks 977..) ----------------
// R9: prep and hists are data-independent (prep: emb/W1/W2; hists: ei/batch)
// but were serialized in-stream. One kernel, block-range split -> they overlap
// (BW-heavy prep hides under the atomic-heavy hists). w2t k-index is in
// P-POSITION space: node_gemm stores position p = w*128 + c*8 + n4 holding
// original channel pi(p) = (p&~127)|((p&7)<<4)|((p>>3)&15); stats are
// position-wise (self-consistent); only W2's k-index compensates.
__global__ void prep_hists(const float* __restrict__ emb, const float* __restrict__ W1,
                           const float* __restrict__ W2,
                           const int* __restrict__ ei, const int* __restrict__ batch,
                           unsigned short* __restrict__ emb_bf,
                           unsigned short* __restrict__ w1tn, unsigned short* __restrict__ w2t,
                           unsigned* __restrict__ hist, unsigned* __restrict__ chist){
  __shared__ unsigned h[NG];
  int t = threadIdx.x;
  if (blockIdx.x < HBLK){
    h[t] = 0; h[t + 256] = 0;
    __syncthreads();
    for (int i = 0; i < 4; i++){
      int e = blockIdx.x * 1024 + i * 256 + t;
      if (e < EDGES){
        int cn = ei[e];
        atomicAdd(&chist[cn], 1u);
        atomicAdd(&h[batch[cn]], 1u);
      }
    }
    __syncthreads();
    atomicAdd(&hist[t], h[t]);
    atomicAdd(&hist[t + 256], h[t + 256]);
  } else {
    int i = (blockIdx.x - HBLK) * 256 + t;
    if (i < NNODES * 64){
      emb_bf[i] = f2bf(emb[i]);
    } else {
      int j = i - NNODES * 64;
      if (j < 32768){
        int jj = j >> 6, k = j & 63;
        float v = (jj < 256) ? W1[k * 256 + jj] : W1[(k + 64) * 256 + (jj - 256)];
        w1tn[j] = f2bf(v);
      } else {
        int jj = j - 32768;
        if (jj < 16384){
          int n = jj >> 8, p = jj & 255;
          int korig = (p & ~127) | ((p & 7) << 4) | ((p >> 3) & 15);
          w2t[jj] = f2bf(W2[korig * 64 + n]);
        }
      }
    }
  }
}

__global__ void col_scan1(const unsigned* __restrict__ chist, unsigned* __restrict__ cpre,
                          unsigned* __restrict__ bsum){
  __shared__ unsigned s[256];
  int t = threadIdx.x;
  int i = blockIdx.x * 256 + t;
  unsigned v = (i < NNODES) ? chist[i] : 0u;
  s[t] = v;
  __syncthreads();
  for (int o = 1; o < 256; o <<= 1){
    unsigned u = (t >= o) ? s[t - o] : 0u;
    __syncthreads();
    s[t] += u;
    __syncthreads();
  }
  cpre[i] = s[t] - v;                 // exclusive within block
  if (t == 255) bsum[blockIdx.x] = s[255];
}

__global__ void col_scan2(unsigned* __restrict__ bsum){   // 196 partials, 1 block
  __shared__ unsigned s[256];
  int t = threadIdx.x;
  unsigned v = (t < 196) ? bsum[t] : 0u;
  s[t] = v;
  __syncthreads();
  for (int o = 1; o < 256; o <<= 1){
    unsigned u = (t >= o) ? s[t - o] : 0u;
    __syncthreads();
    s[t] += u;
    __syncthreads();
  }
  if (t < 196) bsum[t] = s[t] - v;    // exclusive block offsets
}

// ---------------- merged: col_scatter (blocks 0..976) + node_gemm (blocks 977..) ----------------
// scatter: col_scan3 folded in — cpre holds intra-block exclusive prefix
// (cursor), bsum holds exclusive block offsets; global pos = intra + bsum.
// gemm: packed epilogue — lane (c,q) stores its 8 n4 accs as one 16B uint4 at
// position w*128 + c*8 (16 stores/wave vs 128 scalar 2B). Independent inputs
// (scatter: cpre/bsum/ei/batch; gemm: emb_bf/w1tn) -> overlap in one launch.
__global__ __launch_bounds__(256) void scat_gemm(
    const int* __restrict__ ei, const int* __restrict__ batch,
    unsigned* __restrict__ cpre, const unsigned* __restrict__ bsum,
    int4* __restrict__ emeta,
    const unsigned short* __restrict__ emb_bf, const unsigned short* __restrict__ w1tn,
    unsigned short* __restrict__ P)
{
  __shared__ unsigned short As[64 * 72];   // 64 nodes x 64 k, +8 pad (gemm only)
  int t = threadIdx.x;
  if (blockIdx.x < HBLK){
    for (int i = 0; i < 4; i++){
      int e = blockIdx.x * 1024 + i * 256 + t;
      if (e < EDGES){
        int cn = ei[e];
        int pos = (int)atomicAdd(&cpre[cn], 1u) + (int)bsum[cn >> 8];
        emeta[pos] = make_int4(cn, ei[EDGES + e], batch[cn], e);
      }
    }
    return;
  }
  int n0 = (blockIdx.x - HBLK) * 64;
  {
    int nl = t >> 2, part = t & 3;
    int node = n0 + nl; if (node >= NNODES) node = 0;
    const int4* src = (const int4*)(emb_bf + node * 64 + part * 16);
    int4* dst = (int4*)(As + nl * 72 + part * 16);
    dst[0] = src[0]; dst[1] = src[1];
  }
  __syncthreads();
  int w = t >> 6, lane = t & 63, q = lane >> 4, c = lane & 15;
  f32x4 acc[4][8];
  for (int a = 0; a < 4; a++) for (int b = 0; b < 8; b++) for (int r = 0; r < 4; r++) acc[a][b][r] = 0.f;
  for (int k0 = 0; k0 < 64; k0 += 32){
    bf16x8 af[4];
    for (int tt = 0; tt < 4; tt++) af[tt] = *(const bf16x8*)(As + (tt * 16 + c) * 72 + k0 + q * 8);
    for (int n4 = 0; n4 < 8; n4++){
      bf16x8 bw = *(const bf16x8*)(w1tn + (w * 128 + n4 * 16 + c) * 64 + k0 + q * 8);
      for (int tt = 0; tt < 4; tt++)
        acc[tt][n4] = __builtin_amdgcn_mfma_f32_16x16x32_bf16(af[tt], bw, acc[tt][n4], 0, 0, 0);
    }
  }
  for (int tt = 0; tt < 4; tt++){
    for (int r = 0; r < 4; r++){
      int node = n0 + tt * 16 + q * 4 + r;
      if (node < NNODES){
        uint4 pk;
        pk.x = pk2bf(acc[tt][0][r], acc[tt][1][r]);
        pk.y = pk2bf(acc[tt][2][r], acc[tt][3][r]);
        pk.z = pk2bf(acc[tt][4][r], acc[tt][5][r]);
        pk.w = pk2bf(acc[tt][6][r], acc[tt][7][r]);
        *(uint4*)(P + (size_t)node * 512 + w * 128 + c * 8) = pk;
      }
    }
  }
}

// ---------------- K1: gather + segmented stats1 ----------------
// 8 tiles/block (512 edges), 2 tiles/wave; <=2 graphs per block (col-sorted).
// LDS 2-slot accumulation, one set of global atomics per block. (R1 form — best.)
// Channel indices here are P-POSITIONS (permuted space) — self-consistent.
__global__ __launch_bounds__(256, 5) void k1_gather(
    const unsigned short* __restrict__ P, const int4* __restrict__ emeta,
    float* __restrict__ sum1, float* __restrict__ sqs1)
{
  __shared__ float ls[1024];   // [slot:2][sum/sqs:2][ch:256]
  int t = threadIdx.x;
  int bid = xcd_swizzle(blockIdx.x, gridDim.x);
  int tile0 = bid * 8;
  for (int i = t; i < 1024; i += 256) ls[i] = 0.f;
  int s0 = emeta[tile0 * 64].z;
  int elast = tile0 * 64 + 511; if (elast >= EDGES) elast = EDGES - 1;
  int s1 = emeta[elast].z;
  __syncthreads();

  int w = t >> 6, lane = t & 63, c4 = lane * 4;

  float sm0 = 0.f, sm1 = 0.f, sm2 = 0.f, sm3 = 0.f;
  float q0 = 0.f, q1 = 0.f, q2 = 0.f, q3 = 0.f;
  int curs = -1;   // seg currently held in the register accumulators

  auto FLUSH = [&](int s){
    if (s == s0 || s == s1){
      float* base = ls + ((s == s0) ? 0 : 512) + c4;
      atomicAdd(base + 0, sm0); atomicAdd(base + 1, sm1);
      atomicAdd(base + 2, sm2); atomicAdd(base + 3, sm3);
      atomicAdd(base + 256, q0); atomicAdd(base + 257, q1);
      atomicAdd(base + 258, q2); atomicAdd(base + 259, q3);
    } else {  // safety net: >2 segs in block (practically impossible)
      float* sp = sum1 + s * 256 + c4;
      float* qp = sqs1 + s * 256 + c4;
      atomicAdd(sp + 0, sm0); atomicAdd(sp + 1, sm1); atomicAdd(sp + 2, sm2); atomicAdd(sp + 3, sm3);
      atomicAdd(qp + 0, q0);  atomicAdd(qp + 1, q1);  atomicAdd(qp + 2, q2);  atomicAdd(qp + 3, q3);
    }
    sm0 = sm1 = sm2 = sm3 = 0.f; q0 = q1 = q2 = q3 = 0.f;
  };

  for (int ti = 0; ti < 2; ti++){
    int tile = tile0 + w * 2 + ti;
    if (tile >= NTILES) continue;
    int4 me = emeta[tile * 64 + lane];
    int sseg = __builtin_amdgcn_readlane(me.z, 0);
    bool uni = (__ballot(me.z == sseg) == ~0ull);
    if (uni){
      if (sseg != curs){
        if (curs >= 0) FLUSH(curs);
        curs = sseg;
      }
      // rolling prefetch: 3 groups of 4 edges in flight (rows + cols)
      ushort4 rv[3][4], cv[3][4];
      #pragma unroll
      for (int g = 0; g < 2; g++){
        #pragma unroll
        for (int j = 0; j < 4; j++){
          int e = g * 4 + j;
          int re = __builtin_amdgcn_readlane(me.y, e);
          int ce = __builtin_amdgcn_readlane(me.x, e);
          rv[g][j] = *(const ushort4*)(P + (size_t)re * 512 + 256 + c4);
          cv[g][j] = *(const ushort4*)(P + (size_t)ce * 512 + c4);
        }
      }
      #pragma unroll
      for (int g = 0; g < 16; g++){
        if (g < 14){
          int bn = (g + 2) % 3;
          #pragma unroll
          for (int j = 0; j < 4; j++){
            int e = (g + 2) * 4 + j;
            int re = __builtin_amdgcn_readlane(me.y, e);
            int ce = __builtin_amdgcn_readlane(me.x, e);
            rv[bn][j] = *(const ushort4*)(P + (size_t)re * 512 + 256 + c4);
            cv[bn][j] = *(const ushort4*)(P + (size_t)ce * 512 + c4);
          }
        }
        int b = g % 3;
        #pragma unroll
        for (int j = 0; j < 4; j++){
          float x0 = bf2f(cv[b][j].x) + bf2f(rv[b][j].x);
          float x1 = bf2f(cv[b][j].y) + bf2f(rv[b][j].y);
          float x2v = bf2f(cv[b][j].z) + bf2f(rv[b][j].z);
          float x3 = bf2f(cv[b][j].w) + bf2f(rv[b][j].w);
          sm0 += x0; q0 += x0 * x0;
          sm1 += x1; q1 += x1 * x1;
          sm2 += x2v; q2 += x2v * x2v;
          sm3 += x3; q3 += x3 * x3;
        }
      }
    } else {
      // rare (~3% of tiles): seg changes inside the tile — serial path
      int cprev = -1;
      ushort4 a = make_ushort4(0, 0, 0, 0);
      for (int e = 0; e < 64; e++){
        int ce = __builtin_amdgcn_readlane(me.x, e);
        int re = __builtin_amdgcn_readlane(me.y, e);
        int s = __builtin_amdgcn_readlane(me.z, e);
        if (s != curs){
          if (curs >= 0) FLUSH(curs);
          curs = s;
        }
        if (ce != cprev){ a = *(const ushort4*)(P + (size_t)ce * 512 + c4); cprev = ce; }
        ushort4 b = *(const ushort4*)(P + (size_t)re * 512 + 256 + c4);
        float x0 = bf2f(a.x) + bf2f(b.x);
        float x1 = bf2f(a.y) + bf2f(b.y);
        float x2v = bf2f(a.z) + bf2f(b.z);
        float x3 = bf2f(a.w) + bf2f(b.w);
        sm0 += x0; q0 += x0 * x0;
        sm1 += x1; q1 += x1 * x1;
        sm2 += x2v; q2 += x2v * x2v;
        sm3 += x3; q3 += x3 * x3;
      }
    }
  }
  if (curs >= 0) FLUSH(curs);

  __syncthreads();
  // block-level emit: thread t owns channel t
  atomicAdd(&sum1[s0 * 256 + t], ls[t]);
  atomicAdd(&sqs1[s0 * 256 + t], ls[256 + t]);
  if (s1 != s0){
    atomicAdd(&sum1[s1 * 256 + t], ls[512 + t]);
    atomicAdd(&sqs1[s1 * 256 + t], ls[768 + t]);
  }
}

// ---------------- finalize: emit rstd and mean*rstd ----------------
__global__ void finalize1(const float* __restrict__ sum1, const float* __restrict__ sqs1,
                          const unsigned* __restrict__ hist, float* __restrict__ r1,
                          float* __restrict__ mr1){
  int i = blockIdx.x * 256 + threadIdx.x;   // 512*256
  int g = i >> 8;
  float cnt = fmaxf((float)hist[g], 1.f);
  float m = sum1[i] / cnt;
  float v = sqs1[i] / cnt - m * m;
  v = fmaxf(v, 0.f);
  float r = rsqrtf(v + 1e-5f);
  r1[i] = r;
  mr1[i] = m * r;
}

__global__ void finalize2(const float* __restrict__ sum2, const float* __restrict__ sqs2,
                          const unsigned* __restrict__ hist, float* __restrict__ r2,
                          float* __restrict__ mr2){
  int i = blockIdx.x * 256 + threadIdx.x;   // 512*64
  int g = i >> 6;
  float cnt = fmaxf((float)hist[g], 1.f);
  float m = sum2[i] / cnt;
  float v = sqs2[i] / cnt - m * m;
  v = fmaxf(v, 0.f);
  float r = rsqrtf(v + 1e-5f);
  r2[i] = r;
  mr2[i] = m * r;
}

// ---------------- K2: gather -> norm/relu -> GEMM2 + stats2 + x2T store ----------------
// R4 structure (best known, 155us): rows staged via global_load_lds (8
// fire-and-forget 16B DMAs/wave), norm reads raw rows from LDS, writes back
// swizzled in-place; cols via the sorted demand-chain; GEMM2 reads Y with
// matching XOR swizzle. w2t is permuted to position-space (see prep).
// R9: x2t stores are NON-TEMPORAL — 133MB write-once stream; keep it from
// thrashing P (51MB) out of L3 (FETCH was 4.6x P's size = ~50% L3 miss).
__global__ __launch_bounds__(256, 4) void k2_fused(
    const unsigned short* __restrict__ P, const unsigned short* __restrict__ w2t,
    const int4* __restrict__ emeta,
    const float* __restrict__ r1, const float* __restrict__ mr1,
    float* __restrict__ sum2, float* __restrict__ sqs2,
    unsigned short* __restrict__ x2t)
{
  __shared__ unsigned short Y[64 * 256];   // raw rows staged linear, then swizzled y1
  __shared__ int segl[64];
  __shared__ short rsegA[64];
  __shared__ unsigned char rloA[65];
  __shared__ int nrunS;
  int t = threadIdx.x;
  int bid = xcd_swizzle(blockIdx.x, gridDim.x);
  int p0 = bid * 64;
  int w = t >> 6, lane = t & 63, q = lane >> 4, c = lane & 15;
  int c4 = lane * 4;
  int elb0 = w * 16;
  int4 me = emeta[p0 + elb0 + (lane & 15)];

  // stage this wave's 16 raw row-halves into Y rows [elb0, elb0+16), linear
  #pragma unroll
  for (int pp = 0; pp < 8; pp++){
    int r0 = __builtin_amdgcn_readlane(me.y, 2 * pp);
    int r1n = __builtin_amdgcn_readlane(me.y, 2 * pp + 1);
    int node = (lane < 32) ? r0 : r1n;
    const unsigned short* g = P + (size_t)node * 512 + 256 + (lane & 31) * 8;
    gload_lds16(g, &Y[(elb0 + 2 * pp) * 256]);
  }

  // issue first col row + norm factors while the DMAs fly
  int cprev = __builtin_amdgcn_readlane(me.x, 0);
  ushort4 a = *(const ushort4*)(P + (size_t)cprev * 512 + c4);
  int s0g = __builtin_amdgcn_readlane(me.z, 0);
  float4 r4  = *(const float4*)(r1  + s0g * 256 + c4);
  float4 mr4 = *(const float4*)(mr1 + s0g * 256 + c4);

  if (t < 64) segl[t] = emeta[p0 + t].z;
  if (w == 0){
    int sN = segl[lane];
    int nxt = (lane < 63) ? segl[lane + 1] : sN;
    unsigned long long mask = __ballot(sN != nxt);
    if (lane == 0){
      if (mask == 0ull){
        nrunS = 1; rloA[0] = 0; rloA[1] = 64; rsegA[0] = (short)sN;
      } else {
        int n = 0, cur = segl[0];
        rsegA[0] = (short)cur; rloA[0] = 0;
        for (int i = 1; i < 64; i++)
          if (segl[i] != cur){ cur = segl[i]; n++; rsegA[n] = (short)cur; rloA[n] = (unsigned char)i; }
        rloA[n + 1] = 64; nrunS = n + 1;
      }
    }
  }
  __syncthreads();   // drains vmcnt(0): all staged rows are in LDS past here
  int nrun = nrunS;
  bool uni = (nrun == 1);

  // read all 16 raw rows (LDS, 2-way-conflict-free), then norm+swizzled write
  ushort4 bb[16];
  #pragma unroll
  for (int e = 0; e < 16; e++)
    bb[e] = *(const ushort4*)(Y + (elb0 + e) * 256 + c4);

  #pragma unroll
  for (int e = 0; e < 16; e++){
    int ce = __builtin_amdgcn_readlane(me.x, e);
    if (ce != cprev){ a = *(const ushort4*)(P + (size_t)ce * 512 + c4); cprev = ce; }
    float4 rr4 = r4, mm4 = mr4;
    if (!uni){
      int s = __builtin_amdgcn_readlane(me.z, e);
      rr4 = *(const float4*)(r1  + s * 256 + c4);
      mm4 = *(const float4*)(mr1 + s * 256 + c4);
    }
    float y0 = fmaxf(0.f, (bf2f(a.x) + bf2f(bb[e].x)) * rr4.x - mm4.x);
    float y1 = fmaxf(0.f, (bf2f(a.y) + bf2f(bb[e].y)) * rr4.y - mm4.y);
    float y2 = fmaxf(0.f, (bf2f(a.z) + bf2f(bb[e].z)) * rr4.z - mm4.z);
    float y3 = fmaxf(0.f, (bf2f(a.w) + bf2f(bb[e].w)) * rr4.w - mm4.w);
    uint2 pk;
    pk.x = pk2bf(y0, y1);
    pk.y = pk2bf(y2, y3);
    int row = elb0 + e;
    // swizzled in-place write: bijective permutation of the row's 512B
    *(uint2*)((char*)Y + row * 512 + ((lane * 8) ^ ((row & 7) << 4))) = pk;
  }
  __syncthreads();

  // GEMM2: wave w owns out-channels [w*16, w*16+16)
  f32x4 acc2[4];
  for (int tt = 0; tt < 4; tt++) for (int r = 0; r < 4; r++) acc2[tt][r] = 0.f;
  int ch2 = w * 16 + c;
  int swzr = (c & 7) << 4;   // (row&7)<<4 with row = tt*16+c: low 3 bits from c only
  for (int kc = 0; kc < 8; kc++){
    bf16x8 bfr = *(const bf16x8*)(w2t + ch2 * 256 + kc * 32 + q * 8);
    int kb = (kc * 64 + q * 16) ^ swzr;   // byte offset within row, swizzled
    for (int tt = 0; tt < 4; tt++){
      bf16x8 afr = *(const bf16x8*)((const char*)Y + (tt * 16 + c) * 512 + kb);
      acc2[tt] = __builtin_amdgcn_mfma_f32_16x16x32_bf16(afr, bfr, acc2[tt], 0, 0, 0);
    }
  }

  if (uni){
    int s = segl[0];
    float sm = 0.f, sq = 0.f;
    for (int tt = 0; tt < 4; tt++)
      for (int r = 0; r < 4; r++){
        float v = acc2[tt][r];
        sm += v; sq += v * v;
      }
    sm += __shfl_xor(sm, 16); sq += __shfl_xor(sq, 16);
    sm += __shfl_xor(sm, 32); sq += __shfl_xor(sq, 32);
    if (q == 0){
      atomicAdd(&sum2[s * 64 + ch2], sm);
      atomicAdd(&sqs2[s * 64 + ch2], sq);
    }
  } else {
    for (int rr = 0; rr < nrun; rr++){
      int s = rsegA[rr], lo = rloA[rr], hi = rloA[rr + 1];
      float sm = 0.f, sq = 0.f;
      for (int tt = 0; tt < 4; tt++){
        int elb = tt * 16 + q * 4;
        for (int r = 0; r < 4; r++){
          int el = elb + r;
          if (el >= lo && el < hi){
            float v = acc2[tt][r];
            sm += v; sq += v * v;
          }
        }
      }
      sm += __shfl_xor(sm, 16); sq += __shfl_xor(sq, 16);
      sm += __shfl_xor(sm, 32); sq += __shfl_xor(sq, 32);
      if (q == 0){
        atomicAdd(&sum2[s * 64 + ch2], sm);
        atomicAdd(&sqs2[s * 64 + ch2], sq);
      }
    }
  }
  // x2T store: [ch][edge], non-temporal (write-once stream, read later by k3)
  for (int tt = 0; tt < 4; tt++){
    uint2 pk;
    pk.x = pk2bf(acc2[tt][0], acc2[tt][1]);
    pk.y = pk2bf(acc2[tt][2], acc2[tt][3]);
    unsigned long long v = (unsigned long long)pk.x | ((unsigned long long)pk.y << 32);
    __builtin_nontemporal_store(v,
        (unsigned long long*)(x2t + (size_t)ch2 * EDGES + p0 + tt * 16 + q * 4));
  }
}

// ---------------- K3: normalize2 + GEMV W3, 4 edges/thread (x2t is [ch][edge]) ----------------
// R9: x2t read non-temporally (read-once stream).
__global__ __launch_bounds__(256) void k3_out(
    const unsigned short* __restrict__ x2t, const int4* __restrict__ emeta,
    const float* __restrict__ r2, const float* __restrict__ mr2,
    const float* __restrict__ W3, const float* __restrict__ b3, float* __restrict__ out)
{
  int pp4 = (blockIdx.x * 256 + threadIdx.x) * 4;
  if (pp4 >= EDGES) return;
  int4 m0 = emeta[pp4 + 0];
  int4 m1 = emeta[pp4 + 1];
  int4 m2 = emeta[pp4 + 2];
  int4 m3 = emeta[pp4 + 3];
  float a0 = 0.f, a1 = 0.f, a2 = 0.f, a3 = 0.f;
  union { unsigned long long u; ushort4 s; } cv;
  if (m0.z == m3.z && m0.z == m1.z && m0.z == m2.z){
    const float* rp = r2  + m0.z * 64;
    const float* mp = mr2 + m0.z * 64;
    #pragma unroll 8
    for (int ch = 0; ch < 64; ch++){
      cv.u = __builtin_nontemporal_load(
          (const unsigned long long*)(x2t + (size_t)ch * EDGES + pp4));
      ushort4 v = cv.s;
      float rr = rp[ch], mm = mp[ch], wv = W3[ch];
      a0 += fmaxf(0.f, bf2f(v.x) * rr - mm) * wv;
      a1 += fmaxf(0.f, bf2f(v.y) * rr - mm) * wv;
      a2 += fmaxf(0.f, bf2f(v.z) * rr - mm) * wv;
      a3 += fmaxf(0.f, bf2f(v.w) * rr - mm) * wv;
    }
  } else {
    #pragma unroll 8
    for (int ch = 0; ch < 64; ch++){
      cv.u = __builtin_nontemporal_load(
          (const unsigned long long*)(x2t + (size_t)ch * EDGES + pp4));
      ushort4 v = cv.s;
      float wv = W3[ch];
      a0 += fmaxf(0.f, bf2f(v.x) * r2[m0.z * 64 + ch] - mr2[m0.z * 64 + ch]) * wv;
      a1 += fmaxf(0.f, bf2f(v.y) * r2[m1.z * 64 + ch] - mr2[m1.z * 64 + ch]) * wv;
      a2 += fmaxf(0.f, bf2f(v.z) * r2[m2.z * 64 + ch] - mr2[m2.z * 64 + ch]) * wv;
      a3 += fmaxf(0.f, bf2f(v.w) * r2[m3.z * 64 + ch] - mr2[m3.z * 64 + ch]) * wv;
    }
  }
  float bv = b3[0];
  out[m0.w] = a0 + bv;
  out[m1.w] = a1 + bv;
  out[m2.w] = a2 + bv;
  out[m3.w] = a3 + bv;
}

// ---------------- launch ----------------
extern "C" void kernel_launch(void* const* d_in, const int* in_sizes, int n_in,
                              void* d_out, int out_size, void* d_ws, size_t ws_size,
                              hipStream_t stream)
{
  (void)in_sizes; (void)n_in; (void)out_size;
  const float* emb = (const float*)d_in[0];
  const float* W1  = (const float*)d_in[1];
  const float* W2  = (const float*)d_in[3];
  const float* W3  = (const float*)d_in[5];
  const float* b3  = (const float*)d_in[6];
  const int* ei    = (const int*)d_in[7];
  const int* batch = (const int*)d_in[8];
  float* out = (float*)d_out;

  char* p = (char*)d_ws;
  size_t off = 0;
  auto take = [&](size_t n) -> char* {
    char* r = p + off;
    off += (n + 255) & ~(size_t)255;
    return r;
  };

  unsigned short* emb_bf = (unsigned short*)take((size_t)NNODES * 64 * 2);
  unsigned short* w1tn   = (unsigned short*)take(32768 * 2);
  unsigned short* w2t    = (unsigned short*)take(16384 * 2);
  int4* emeta = (int4*)take((size_t)EDGES * 16);
  unsigned short* P   = (unsigned short*)take((size_t)NNODES * 512 * 2);
  unsigned short* x2t = (unsigned short*)take((size_t)EDGES * 64 * 2);
  float* r1  = (float*)take(512 * 256 * 4);
  float* mr1 = (float*)take(512 * 256 * 4);
  float* r2  = (float*)take(512 * 64 * 4);
  float* mr2 = (float*)take(512 * 64 * 4);
  unsigned* cpre = (unsigned*)take(NCOLB * 4);
  unsigned* bsum = (unsigned*)take(256 * 4);
  // zero-init region (contiguous)
  char* zbase = p + off;
  unsigned* hist  = (unsigned*)take(NG * 4);
  unsigned* chist = (unsigned*)take(NCOLB * 4);
  float* sum1 = (float*)take(512 * 256 * 4);
  float* sqs1 = (float*)take(512 * 256 * 4);
  float* sum2 = (float*)take(512 * 64 * 4);
  float* sqs2 = (float*)take(512 * 64 * 4);
  size_t zsize = (size_t)((p + off) - zbase);

  if (ws_size < off) return;  // workspace too small — fail loudly via poison

  hipMemsetAsync(zbase, 0, zsize, stream);
  prep_hists<<<HBLK + 12692, 256, 0, stream>>>(emb, W1, W2, ei, batch,
                                               emb_bf, w1tn, w2t, hist, chist);
  col_scan1<<<196, 256, 0, stream>>>(chist, cpre, bsum);
  col_scan2<<<1, 256, 0, stream>>>(bsum);
  scat_gemm<<<HBLK + GBLK, 256, 0, stream>>>(ei, batch, cpre, bsum, emeta,
                                             emb_bf, w1tn, P);
  k1_gather<<<(NTILES + 7) / 8, 256, 0, stream>>>(P, emeta, sum1, sqs1);
  finalize1<<<512, 256, 0, stream>>>(sum1, sqs1, hist, r1, mr1);
  k2_fused<<<NTILES, 256, 0, stream>>>(P, w2t, emeta, r1, mr1, sum2, sqs2, x2t);
  finalize2<<<128, 256, 0, stream>>>(sum2, sqs2, hist, r2, mr2);
  k3_out<<<977, 256, 0, stream>>>(x2t, emeta, r2, mr2, W3, b3, out);
}

// Round 11
// 489.102 us; speedup vs baseline: 1.5635x; 1.0123x over previous
//
#include <hip/hip_runtime.h>
#include <hip/hip_bf16.h>

#define EDGES 1000000
#define NNODES 50000
#define NG 512
#define NTILES 15625  // EDGES/64
#define NCOLB 50176   // col-hist bins rounded to 196*256
#define HBLK 977      // hists/scatter block count (EDGES/1024 rounded up)
#define GBLK 782      // node_gemm block count (NNODES/64 rounded up)

typedef __attribute__((ext_vector_type(8))) short bf16x8;
typedef __attribute__((ext_vector_type(4))) float f32x4;

__device__ __forceinline__ unsigned short f2bf(float f){
  unsigned u = __float_as_uint(f);
  u += 0x7fffu + ((u >> 16) & 1u);
  return (unsigned short)(u >> 16);
}
__device__ __forceinline__ float bf2f(unsigned short h){
  return __uint_as_float(((unsigned)h) << 16);
}
__device__ __forceinline__ unsigned pk2bf(float x, float y){
  __hip_bfloat162 h = __float22bfloat162_rn(make_float2(x, y));
  union { __hip_bfloat162 h; unsigned u; } cv; cv.h = h;
  return cv.u;
}
// fire-and-forget global->LDS DMA, 16B per lane, dest = uniform base + lane*16
__device__ __forceinline__ void gload_lds16(const void* g, void* l){
  __builtin_amdgcn_global_load_lds(
      (const __attribute__((address_space(1))) unsigned int*)g,
      (__attribute__((address_space(3))) unsigned int*)l, 16, 0, 0);
}
// XCD-aware swizzle: contiguous tile ranges per XCD. TRUE BIJECTION.
__device__ __forceinline__ int xcd_swizzle(int bid, int nb){
  int nb8 = nb & ~7;
  if (bid >= nb8) return bid;
  int per = nb8 >> 3;
  return (bid & 7) * per + (bid >> 3);
}

// ---------------- merged: hists (blocks 0..976) + prep (blocks 977..) ----------------
// prep and hists are data-independent -> one kernel, block-range split.
// w2t k-index is in P-POSITION space: node_gemm stores position
// p = w*128 + c*8 + n4 holding original channel
// pi(p) = (p&~127)|((p&7)<<4)|((p>>3)&15); stats are position-wise
// (self-consistent); only W2's k-index compensates.
__global__ void prep_hists(const float* __restrict__ emb, const float* __restrict__ W1,
                           const float* __restrict__ W2,
                           const int* __restrict__ ei, const int* __restrict__ batch,
                           unsigned short* __restrict__ emb_bf,
                           unsigned short* __restrict__ w1tn, unsigned short* __restrict__ w2t,
                           unsigned* __restrict__ hist, unsigned* __restrict__ chist){
  __shared__ unsigned h[NG];
  int t = threadIdx.x;
  if (blockIdx.x < HBLK){
    h[t] = 0; h[t + 256] = 0;
    __syncthreads();
    for (int i = 0; i < 4; i++){
      int e = blockIdx.x * 1024 + i * 256 + t;
      if (e < EDGES){
        int cn = ei[e];
        atomicAdd(&chist[cn], 1u);
        atomicAdd(&h[batch[cn]], 1u);
      }
    }
    __syncthreads();
    atomicAdd(&hist[t], h[t]);
    atomicAdd(&hist[t + 256], h[t + 256]);
  } else {
    int i = (blockIdx.x - HBLK) * 256 + t;
    if (i < NNODES * 64){
      emb_bf[i] = f2bf(emb[i]);
    } else {
      int j = i - NNODES * 64;
      if (j < 32768){
        int jj = j >> 6, k = j & 63;
        float v = (jj < 256) ? W1[k * 256 + jj] : W1[(k + 64) * 256 + (jj - 256)];
        w1tn[j] = f2bf(v);
      } else {
        int jj = j - 32768;
        if (jj < 16384){
          int n = jj >> 8, p = jj & 255;
          int korig = (p & ~127) | ((p & 7) << 4) | ((p >> 3) & 15);
          w2t[jj] = f2bf(W2[korig * 64 + n]);
        }
      }
    }
  }
}

__global__ void col_scan1(const unsigned* __restrict__ chist, unsigned* __restrict__ cpre,
                          unsigned* __restrict__ bsum){
  __shared__ unsigned s[256];
  int t = threadIdx.x;
  int i = blockIdx.x * 256 + t;
  unsigned v = (i < NNODES) ? chist[i] : 0u;
  s[t] = v;
  __syncthreads();
  for (int o = 1; o < 256; o <<= 1){
    unsigned u = (t >= o) ? s[t - o] : 0u;
    __syncthreads();
    s[t] += u;
    __syncthreads();
  }
  cpre[i] = s[t] - v;                 // exclusive within block
  if (t == 255) bsum[blockIdx.x] = s[255];
}

__global__ void col_scan2(unsigned* __restrict__ bsum){   // 196 partials, 1 block
  __shared__ unsigned s[256];
  int t = threadIdx.x;
  unsigned v = (t < 196) ? bsum[t] : 0u;
  s[t] = v;
  __syncthreads();
  for (int o = 1; o < 256; o <<= 1){
    unsigned u = (t >= o) ? s[t - o] : 0u;
    __syncthreads();
    s[t] += u;
    __syncthreads();
  }
  if (t < 196) bsum[t] = s[t] - v;    // exclusive block offsets
}

// ---------------- merged: col_scatter (blocks 0..976) + node_gemm (blocks 977..) ----------------
// scatter: col_scan3 folded in — global pos = intra-block cursor + bsum[blk].
// gemm: packed epilogue — lane (c,q) stores its 8 n4 accs as one 16B uint4 at
// position w*128 + c*8 (16 stores/wave vs 128 scalar 2B).
__global__ __launch_bounds__(256) void scat_gemm(
    const int* __restrict__ ei, const int* __restrict__ batch,
    unsigned* __restrict__ cpre, const unsigned* __restrict__ bsum,
    int4* __restrict__ emeta,
    const unsigned short* __restrict__ emb_bf, const unsigned short* __restrict__ w1tn,
    unsigned short* __restrict__ P)
{
  __shared__ unsigned short As[64 * 72];   // 64 nodes x 64 k, +8 pad (gemm only)
  int t = threadIdx.x;
  if (blockIdx.x < HBLK){
    for (int i = 0; i < 4; i++){
      int e = blockIdx.x * 1024 + i * 256 + t;
      if (e < EDGES){
        int cn = ei[e];
        int pos = (int)atomicAdd(&cpre[cn], 1u) + (int)bsum[cn >> 8];
        emeta[pos] = make_int4(cn, ei[EDGES + e], batch[cn], e);
      }
    }
    return;
  }
  int n0 = (blockIdx.x - HBLK) * 64;
  {
    int nl = t >> 2, part = t & 3;
    int node = n0 + nl; if (node >= NNODES) node = 0;
    const int4* src = (const int4*)(emb_bf + node * 64 + part * 16);
    int4* dst = (int4*)(As + nl * 72 + part * 16);
    dst[0] = src[0]; dst[1] = src[1];
  }
  __syncthreads();
  int w = t >> 6, lane = t & 63, q = lane >> 4, c = lane & 15;
  f32x4 acc[4][8];
  for (int a = 0; a < 4; a++) for (int b = 0; b < 8; b++) for (int r = 0; r < 4; r++) acc[a][b][r] = 0.f;
  for (int k0 = 0; k0 < 64; k0 += 32){
    bf16x8 af[4];
    for (int tt = 0; tt < 4; tt++) af[tt] = *(const bf16x8*)(As + (tt * 16 + c) * 72 + k0 + q * 8);
    for (int n4 = 0; n4 < 8; n4++){
      bf16x8 bw = *(const bf16x8*)(w1tn + (w * 128 + n4 * 16 + c) * 64 + k0 + q * 8);
      for (int tt = 0; tt < 4; tt++)
        acc[tt][n4] = __builtin_amdgcn_mfma_f32_16x16x32_bf16(af[tt], bw, acc[tt][n4], 0, 0, 0);
    }
  }
  for (int tt = 0; tt < 4; tt++){
    for (int r = 0; r < 4; r++){
      int node = n0 + tt * 16 + q * 4 + r;
      if (node < NNODES){
        uint4 pk;
        pk.x = pk2bf(acc[tt][0][r], acc[tt][1][r]);
        pk.y = pk2bf(acc[tt][2][r], acc[tt][3][r]);
        pk.z = pk2bf(acc[tt][4][r], acc[tt][5][r]);
        pk.w = pk2bf(acc[tt][6][r], acc[tt][7][r]);
        *(uint4*)(P + (size_t)node * 512 + w * 128 + c * 8) = pk;
      }
    }
  }
}

// ---------------- K1: gather + segmented stats1 ----------------
// 8 tiles/block (512 edges), 2 tiles/wave; <=2 graphs per block (col-sorted).
// LDS 2-slot accumulation, one set of global atomics per block. (R1 form — best.)
__global__ __launch_bounds__(256, 5) void k1_gather(
    const unsigned short* __restrict__ P, const int4* __restrict__ emeta,
    float* __restrict__ sum1, float* __restrict__ sqs1)
{
  __shared__ float ls[1024];   // [slot:2][sum/sqs:2][ch:256]
  int t = threadIdx.x;
  int bid = xcd_swizzle(blockIdx.x, gridDim.x);
  int tile0 = bid * 8;
  for (int i = t; i < 1024; i += 256) ls[i] = 0.f;
  int s0 = emeta[tile0 * 64].z;
  int elast = tile0 * 64 + 511; if (elast >= EDGES) elast = EDGES - 1;
  int s1 = emeta[elast].z;
  __syncthreads();

  int w = t >> 6, lane = t & 63, c4 = lane * 4;

  float sm0 = 0.f, sm1 = 0.f, sm2 = 0.f, sm3 = 0.f;
  float q0 = 0.f, q1 = 0.f, q2 = 0.f, q3 = 0.f;
  int curs = -1;   // seg currently held in the register accumulators

  auto FLUSH = [&](int s){
    if (s == s0 || s == s1){
      float* base = ls + ((s == s0) ? 0 : 512) + c4;
      atomicAdd(base + 0, sm0); atomicAdd(base + 1, sm1);
      atomicAdd(base + 2, sm2); atomicAdd(base + 3, sm3);
      atomicAdd(base + 256, q0); atomicAdd(base + 257, q1);
      atomicAdd(base + 258, q2); atomicAdd(base + 259, q3);
    } else {  // safety net: >2 segs in block (practically impossible)
      float* sp = sum1 + s * 256 + c4;
      float* qp = sqs1 + s * 256 + c4;
      atomicAdd(sp + 0, sm0); atomicAdd(sp + 1, sm1); atomicAdd(sp + 2, sm2); atomicAdd(sp + 3, sm3);
      atomicAdd(qp + 0, q0);  atomicAdd(qp + 1, q1);  atomicAdd(qp + 2, q2);  atomicAdd(qp + 3, q3);
    }
    sm0 = sm1 = sm2 = sm3 = 0.f; q0 = q1 = q2 = q3 = 0.f;
  };

  for (int ti = 0; ti < 2; ti++){
    int tile = tile0 + w * 2 + ti;
    if (tile >= NTILES) continue;
    int4 me = emeta[tile * 64 + lane];
    int sseg = __builtin_amdgcn_readlane(me.z, 0);
    bool uni = (__ballot(me.z == sseg) == ~0ull);
    if (uni){
      if (sseg != curs){
        if (curs >= 0) FLUSH(curs);
        curs = sseg;
      }
      // rolling prefetch: 3 groups of 4 edges in flight (rows + cols)
      ushort4 rv[3][4], cv[3][4];
      #pragma unroll
      for (int g = 0; g < 2; g++){
        #pragma unroll
        for (int j = 0; j < 4; j++){
          int e = g * 4 + j;
          int re = __builtin_amdgcn_readlane(me.y, e);
          int ce = __builtin_amdgcn_readlane(me.x, e);
          rv[g][j] = *(const ushort4*)(P + (size_t)re * 512 + 256 + c4);
          cv[g][j] = *(const ushort4*)(P + (size_t)ce * 512 + c4);
        }
      }
      #pragma unroll
      for (int g = 0; g < 16; g++){
        if (g < 14){
          int bn = (g + 2) % 3;
          #pragma unroll
          for (int j = 0; j < 4; j++){
            int e = (g + 2) * 4 + j;
            int re = __builtin_amdgcn_readlane(me.y, e);
            int ce = __builtin_amdgcn_readlane(me.x, e);
            rv[bn][j] = *(const ushort4*)(P + (size_t)re * 512 + 256 + c4);
            cv[bn][j] = *(const ushort4*)(P + (size_t)ce * 512 + c4);
          }
        }
        int b = g % 3;
        #pragma unroll
        for (int j = 0; j < 4; j++){
          float x0 = bf2f(cv[b][j].x) + bf2f(rv[b][j].x);
          float x1 = bf2f(cv[b][j].y) + bf2f(rv[b][j].y);
          float x2v = bf2f(cv[b][j].z) + bf2f(rv[b][j].z);
          float x3 = bf2f(cv[b][j].w) + bf2f(rv[b][j].w);
          sm0 += x0; q0 += x0 * x0;
          sm1 += x1; q1 += x1 * x1;
          sm2 += x2v; q2 += x2v * x2v;
          sm3 += x3; q3 += x3 * x3;
        }
      }
    } else {
      // rare (~3% of tiles): seg changes inside the tile — serial path
      int cprev = -1;
      ushort4 a = make_ushort4(0, 0, 0, 0);
      for (int e = 0; e < 64; e++){
        int ce = __builtin_amdgcn_readlane(me.x, e);
        int re = __builtin_amdgcn_readlane(me.y, e);
        int s = __builtin_amdgcn_readlane(me.z, e);
        if (s != curs){
          if (curs >= 0) FLUSH(curs);
          curs = s;
        }
        if (ce != cprev){ a = *(const ushort4*)(P + (size_t)ce * 512 + c4); cprev = ce; }
        ushort4 b = *(const ushort4*)(P + (size_t)re * 512 + 256 + c4);
        float x0 = bf2f(a.x) + bf2f(b.x);
        float x1 = bf2f(a.y) + bf2f(b.y);
        float x2v = bf2f(a.z) + bf2f(b.z);
        float x3 = bf2f(a.w) + bf2f(b.w);
        sm0 += x0; q0 += x0 * x0;
        sm1 += x1; q1 += x1 * x1;
        sm2 += x2v; q2 += x2v * x2v;
        sm3 += x3; q3 += x3 * x3;
      }
    }
  }
  if (curs >= 0) FLUSH(curs);

  __syncthreads();
  // block-level emit: thread t owns channel t
  atomicAdd(&sum1[s0 * 256 + t], ls[t]);
  atomicAdd(&sqs1[s0 * 256 + t], ls[256 + t]);
  if (s1 != s0){
    atomicAdd(&sum1[s1 * 256 + t], ls[512 + t]);
    atomicAdd(&sqs1[s1 * 256 + t], ls[768 + t]);
  }
}

// ---------------- finalize: emit rstd and mean*rstd ----------------
__global__ void finalize1(const float* __restrict__ sum1, const float* __restrict__ sqs1,
                          const unsigned* __restrict__ hist, float* __restrict__ r1,
                          float* __restrict__ mr1){
  int i = blockIdx.x * 256 + threadIdx.x;   // 512*256
  int g = i >> 8;
  float cnt = fmaxf((float)hist[g], 1.f);
  float m = sum1[i] / cnt;
  float v = sqs1[i] / cnt - m * m;
  v = fmaxf(v, 0.f);
  float r = rsqrtf(v + 1e-5f);
  r1[i] = r;
  mr1[i] = m * r;
}

__global__ void finalize2(const float* __restrict__ sum2, const float* __restrict__ sqs2,
                          const unsigned* __restrict__ hist, float* __restrict__ r2,
                          float* __restrict__ mr2){
  int i = blockIdx.x * 256 + threadIdx.x;   // 512*64
  int g = i >> 6;
  float cnt = fmaxf((float)hist[g], 1.f);
  float m = sum2[i] / cnt;
  float v = sqs2[i] / cnt - m * m;
  v = fmaxf(v, 0.f);
  float r = rsqrtf(v + 1e-5f);
  r2[i] = r;
  mr2[i] = m * r;
}

// ---------------- K2: gather -> norm/relu -> GEMM2 + stats2 + x2T store ----------------
// R4 structure (best known): rows via global_load_lds, norm reads raw rows
// from LDS and writes back swizzled in-place; cols via sorted demand-chain;
// GEMM2 reads Y with matching XOR swizzle; w2t in position-space.
// R10/R11: NT stores REVERTED (R9: +77MB WRITE amplification, +4us). Col-half
// bf16->f32 converts hoisted into the col-change branch (cols sorted, ~1-2
// changes per 16 edges): saves ~56 VALU cvt/lane-tile in a VALU-issue-bound
// kernel (56% VALUBusy).
__global__ __launch_bounds__(256, 4) void k2_fused(
    const unsigned short* __restrict__ P, const unsigned short* __restrict__ w2t,
    const int4* __restrict__ emeta,
    const float* __restrict__ r1, const float* __restrict__ mr1,
    float* __restrict__ sum2, float* __restrict__ sqs2,
    unsigned short* __restrict__ x2t)
{
  __shared__ unsigned short Y[64 * 256];   // raw rows staged linear, then swizzled y1
  __shared__ int segl[64];
  __shared__ short rsegA[64];
  __shared__ unsigned char rloA[65];
  __shared__ int nrunS;
  int t = threadIdx.x;
  int bid = xcd_swizzle(blockIdx.x, gridDim.x);
  int p0 = bid * 64;
  int w = t >> 6, lane = t & 63, q = lane >> 4, c = lane & 15;
  int c4 = lane * 4;
  int elb0 = w * 16;
  int4 me = emeta[p0 + elb0 + (lane & 15)];

  // stage this wave's 16 raw row-halves into Y rows [elb0, elb0+16), linear
  #pragma unroll
  for (int pp = 0; pp < 8; pp++){
    int r0 = __builtin_amdgcn_readlane(me.y, 2 * pp);
    int r1n = __builtin_amdgcn_readlane(me.y, 2 * pp + 1);
    int node = (lane < 32) ? r0 : r1n;
    const unsigned short* g = P + (size_t)node * 512 + 256 + (lane & 31) * 8;
    gload_lds16(g, &Y[(elb0 + 2 * pp) * 256]);
  }

  // issue first col row + norm factors while the DMAs fly
  int cprev = __builtin_amdgcn_readlane(me.x, 0);
  ushort4 a = *(const ushort4*)(P + (size_t)cprev * 512 + c4);
  float ax = bf2f(a.x), ay = bf2f(a.y), az = bf2f(a.z), aw = bf2f(a.w);
  int s0g = __builtin_amdgcn_readlane(me.z, 0);
  float4 r4  = *(const float4*)(r1  + s0g * 256 + c4);
  float4 mr4 = *(const float4*)(mr1 + s0g * 256 + c4);

  if (t < 64) segl[t] = emeta[p0 + t].z;
  if (w == 0){
    int sN = segl[lane];
    int nxt = (lane < 63) ? segl[lane + 1] : sN;
    unsigned long long mask = __ballot(sN != nxt);
    if (lane == 0){
      if (mask == 0ull){
        nrunS = 1; rloA[0] = 0; rloA[1] = 64; rsegA[0] = (short)sN;
      } else {
        int n = 0, cur = segl[0];
        rsegA[0] = (short)cur; rloA[0] = 0;
        for (int i = 1; i < 64; i++)
          if (segl[i] != cur){ cur = segl[i]; n++; rsegA[n] = (short)cur; rloA[n] = (unsigned char)i; }
        rloA[n + 1] = 64; nrunS = n + 1;
      }
    }
  }
  __syncthreads();   // drains vmcnt(0): all staged rows are in LDS past here
  int nrun = nrunS;
  bool uni = (nrun == 1);

  // read all 16 raw rows (LDS, 2-way-conflict-free), then norm+swizzled write
  ushort4 bb[16];
  #pragma unroll
  for (int e = 0; e < 16; e++)
    bb[e] = *(const ushort4*)(Y + (elb0 + e) * 256 + c4);

  #pragma unroll
  for (int e = 0; e < 16; e++){
    int ce = __builtin_amdgcn_readlane(me.x, e);
    if (ce != cprev){
      a = *(const ushort4*)(P + (size_t)ce * 512 + c4); cprev = ce;
      ax = bf2f(a.x); ay = bf2f(a.y); az = bf2f(a.z); aw = bf2f(a.w);
    }
    float4 rr4 = r4, mm4 = mr4;
    if (!uni){
      int s = __builtin_amdgcn_readlane(me.z, e);
      rr4 = *(const float4*)(r1  + s * 256 + c4);
      mm4 = *(const float4*)(mr1 + s * 256 + c4);
    }
    float y0 = fmaxf(0.f, (ax + bf2f(bb[e].x)) * rr4.x - mm4.x);
    float y1 = fmaxf(0.f, (ay + bf2f(bb[e].y)) * rr4.y - mm4.y);
    float y2 = fmaxf(0.f, (az + bf2f(bb[e].z)) * rr4.z - mm4.z);
    float y3 = fmaxf(0.f, (aw + bf2f(bb[e].w)) * rr4.w - mm4.w);
    uint2 pk;
    pk.x = pk2bf(y0, y1);
    pk.y = pk2bf(y2, y3);
    int row = elb0 + e;
    // swizzled in-place write: bijective permutation of the row's 512B
    *(uint2*)((char*)Y + row * 512 + ((lane * 8) ^ ((row & 7) << 4))) = pk;
  }
  __syncthreads();

  // GEMM2: wave w owns out-channels [w*16, w*16+16)
  f32x4 acc2[4];
  for (int tt = 0; tt < 4; tt++) for (int r = 0; r < 4; r++) acc2[tt][r] = 0.f;
  int ch2 = w * 16 + c;
  int swzr = (c & 7) << 4;   // (row&7)<<4 with row = tt*16+c: low 3 bits from c only
  for (int kc = 0; kc < 8; kc++){
    bf16x8 bfr = *(const bf16x8*)(w2t + ch2 * 256 + kc * 32 + q * 8);
    int kb = (kc * 64 + q * 16) ^ swzr;   // byte offset within row, swizzled
    for (int tt = 0; tt < 4; tt++){
      bf16x8 afr = *(const bf16x8*)((const char*)Y + (tt * 16 + c) * 512 + kb);
      acc2[tt] = __builtin_amdgcn_mfma_f32_16x16x32_bf16(afr, bfr, acc2[tt], 0, 0, 0);
    }
  }

  if (uni){
    int s = segl[0];
    float sm = 0.f, sq = 0.f;
    for (int tt = 0; tt < 4; tt++)
      for (int r = 0; r < 4; r++){
        float v = acc2[tt][r];
        sm += v; sq += v * v;
      }
    sm += __shfl_xor(sm, 16); sq += __shfl_xor(sq, 16);
    sm += __shfl_xor(sm, 32); sq += __shfl_xor(sq, 32);
    if (q == 0){
      atomicAdd(&sum2[s * 64 + ch2], sm);
      atomicAdd(&sqs2[s * 64 + ch2], sq);
    }
  } else {
    for (int rr = 0; rr < nrun; rr++){
      int s = rsegA[rr], lo = rloA[rr], hi = rloA[rr + 1];
      float sm = 0.f, sq = 0.f;
      for (int tt = 0; tt < 4; tt++){
        int elb = tt * 16 + q * 4;
        for (int r = 0; r < 4; r++){
          int el = elb + r;
          if (el >= lo && el < hi){
            float v = acc2[tt][r];
            sm += v; sq += v * v;
          }
        }
      }
      sm += __shfl_xor(sm, 16); sq += __shfl_xor(sq, 16);
      sm += __shfl_xor(sm, 32); sq += __shfl_xor(sq, 32);
      if (q == 0){
        atomicAdd(&sum2[s * 64 + ch2], sm);
        atomicAdd(&sqs2[s * 64 + ch2], sq);
      }
    }
  }
  // x2T store: [ch][edge], plain stores (NT was write-amplifying — R9)
  for (int tt = 0; tt < 4; tt++){
    uint2 pk;
    pk.x = pk2bf(acc2[tt][0], acc2[tt][1]);
    pk.y = pk2bf(acc2[tt][2], acc2[tt][3]);
    *(uint2*)(x2t + (size_t)ch2 * EDGES + p0 + tt * 16 + q * 4) = pk;
  }
}

// ---------------- K3: normalize2 + GEMV W3, 4 edges/thread (x2t is [ch][edge]) ----------------
__global__ __launch_bounds__(256) void k3_out(
    const unsigned short* __restrict__ x2t, const int4* __restrict__ emeta,
    const float* __restrict__ r2, const float* __restrict__ mr2,
    const float* __restrict__ W3, const float* __restrict__ b3, float* __restrict__ out)
{
  int pp4 = (blockIdx.x * 256 + threadIdx.x) * 4;
  if (pp4 >= EDGES) return;
  int4 m0 = emeta[pp4 + 0];
  int4 m1 = emeta[pp4 + 1];
  int4 m2 = emeta[pp4 + 2];
  int4 m3 = emeta[pp4 + 3];
  float a0 = 0.f, a1 = 0.f, a2 = 0.f, a3 = 0.f;
  if (m0.z == m3.z && m0.z == m1.z && m0.z == m2.z){
    const float* rp = r2  + m0.z * 64;
    const float* mp = mr2 + m0.z * 64;
    #pragma unroll 8
    for (int ch = 0; ch < 64; ch++){
      ushort4 v = *(const ushort4*)(x2t + (size_t)ch * EDGES + pp4);
      float rr = rp[ch], mm = mp[ch], wv = W3[ch];
      a0 += fmaxf(0.f, bf2f(v.x) * rr - mm) * wv;
      a1 += fmaxf(0.f, bf2f(v.y) * rr - mm) * wv;
      a2 += fmaxf(0.f, bf2f(v.z) * rr - mm) * wv;
      a3 += fmaxf(0.f, bf2f(v.w) * rr - mm) * wv;
    }
  } else {
    #pragma unroll 8
    for (int ch = 0; ch < 64; ch++){
      ushort4 v = *(const ushort4*)(x2t + (size_t)ch * EDGES + pp4);
      float wv = W3[ch];
      a0 += fmaxf(0.f, bf2f(v.x) * r2[m0.z * 64 + ch] - mr2[m0.z * 64 + ch]) * wv;
      a1 += fmaxf(0.f, bf2f(v.y) * r2[m1.z * 64 + ch] - mr2[m1.z * 64 + ch]) * wv;
      a2 += fmaxf(0.f, bf2f(v.z) * r2[m2.z * 64 + ch] - mr2[m2.z * 64 + ch]) * wv;
      a3 += fmaxf(0.f, bf2f(v.w) * r2[m3.z * 64 + ch] - mr2[m3.z * 64 + ch]) * wv;
    }
  }
  float bv = b3[0];
  out[m0.w] = a0 + bv;
  out[m1.w] = a1 + bv;
  out[m2.w] = a2 + bv;
  out[m3.w] = a3 + bv;
}

// ---------------- launch ----------------
extern "C" void kernel_launch(void* const* d_in, const int* in_sizes, int n_in,
                              void* d_out, int out_size, void* d_ws, size_t ws_size,
                              hipStream_t stream)
{
  (void)in_sizes; (void)n_in; (void)out_size;
  const float* emb = (const float*)d_in[0];
  const float* W1  = (const float*)d_in[1];
  const float* W2  = (const float*)d_in[3];
  const float* W3  = (const float*)d_in[5];
  const float* b3  = (const float*)d_in[6];
  const int* ei    = (const int*)d_in[7];
  const int* batch = (const int*)d_in[8];
  float* out = (float*)d_out;

  char* p = (char*)d_ws;
  size_t off = 0;
  auto take = [&](size_t n) -> char* {
    char* r = p + off;
    off += (n + 255) & ~(size_t)255;
    return r;
  };

  unsigned short* emb_bf = (unsigned short*)take((size_t)NNODES * 64 * 2);
  unsigned short* w1tn   = (unsigned short*)take(32768 * 2);
  unsigned short* w2t    = (unsigned short*)take(16384 * 2);
  int4* emeta = (int4*)take((size_t)EDGES * 16);
  unsigned short* P   = (unsigned short*)take((size_t)NNODES * 512 * 2);
  unsigned short* x2t = (unsigned short*)take((size_t)EDGES * 64 * 2);
  float* r1  = (float*)take(512 * 256 * 4);
  float* mr1 = (float*)take(512 * 256 * 4);
  float* r2  = (float*)take(512 * 64 * 4);
  float* mr2 = (float*)take(512 * 64 * 4);
  unsigned* cpre = (unsigned*)take(NCOLB * 4);
  unsigned* bsum = (unsigned*)take(256 * 4);
  // zero-init region (contiguous)
  char* zbase = p + off;
  unsigned* hist  = (unsigned*)take(NG * 4);
  unsigned* chist = (unsigned*)take(NCOLB * 4);
  float* sum1 = (float*)take(512 * 256 * 4);
  float* sqs1 = (float*)take(512 * 256 * 4);
  float* sum2 = (float*)take(512 * 64 * 4);
  float* sqs2 = (float*)take(512 * 64 * 4);
  size_t zsize = (size_t)((p + off) - zbase);

  if (ws_size < off) return;  // workspace too small — fail loudly via poison

  hipMemsetAsync(zbase, 0, zsize, stream);
  prep_hists<<<HBLK + 12692, 256, 0, stream>>>(emb, W1, W2, ei, batch,
                                               emb_bf, w1tn, w2t, hist, chist);
  col_scan1<<<196, 256, 0, stream>>>(chist, cpre, bsum);
  col_scan2<<<1, 256, 0, stream>>>(bsum);
  scat_gemm<<<HBLK + GBLK, 256, 0, stream>>>(ei, batch, cpre, bsum, emeta,
                                             emb_bf, w1tn, P);
  k1_gather<<<(NTILES + 7) / 8, 256, 0, stream>>>(P, emeta, sum1, sqs1);
  finalize1<<<512, 256, 0, stream>>>(sum1, sqs1, hist, r1, mr1);
  k2_fused<<<NTILES, 256, 0, stream>>>(P, w2t, emeta, r1, mr1, sum2, sqs2, x2t);
  finalize2<<<128, 256, 0, stream>>>(sum2, sqs2, hist, r2, mr2);
  k3_out<<<977, 256, 0, stream>>>(x2t, emeta, r2, mr2, W3, b3, out);
}